// Round 1
// baseline (6770.374 us; speedup 1.0000x reference)
//
#include <hip/hip_runtime.h>
#include <cstdint>
#include <cstddef>

#define EPSF 1e-9f

// ---------------- zero ----------------
__global__ __launch_bounds__(256) void fzero(float* __restrict__ p, long n) {
  long i = (long)blockIdx.x * blockDim.x + threadIdx.x;
  long stride = (long)gridDim.x * blockDim.x;
  long n4 = n >> 2;
  float4* p4 = (float4*)p;
  for (long j = i; j < n4; j += stride) p4[j] = make_float4(0.f, 0.f, 0.f, 0.f);
  for (long j = (n4 << 2) + i; j < n; j += stride) p[j] = 0.f;
}

// ---------------- fold rel_att/rel_msg into W ----------------
// Wkf[t][i][h*16+e] = sum_d Wk[t][i][h*16+d] * rel_att[t][h][d][e]   (i==128 -> bias row)
__global__ __launch_bounds__(128) void fuse_w(
    const float* __restrict__ Wk, const float* __restrict__ bk,
    const float* __restrict__ Wv, const float* __restrict__ bv,
    const float* __restrict__ rel_att, const float* __restrict__ rel_msg,
    float* __restrict__ Wkf, float* __restrict__ bkf,
    float* __restrict__ Wvf, float* __restrict__ bvf)
{
  int i = blockIdx.x;   // 0..128 (128 == bias)
  int t = blockIdx.y;   // node type
  int m = blockIdx.z;   // 0=k path, 1=v path
  int c = threadIdx.x;  // output col
  int h = c >> 4, e = c & 15;
  const float* R = (m ? rel_msg : rel_att) + t * 2048 + h * 256;
  const float* srcW = (m ? Wv : Wk) + t * 16384;
  const float* srcB = (m ? bv : bk) + t * 128;
  const float* row = (i < 128) ? (srcW + i * 128) : srcB;
  float acc = 0.f;
#pragma unroll
  for (int d = 0; d < 16; ++d) acc = fmaf(row[h * 16 + d], R[d * 16 + e], acc);
  if (i < 128) (m ? Wvf : Wkf)[t * 16384 + i * 128 + c] = acc;
  else         (m ? bvf : bkf)[t * 128 + c] = acc;
}

// ---------------- f32 GEMM: C[M x 64-slice] = A[M x 128] @ W[128 x 128] + bias ----------------
// block 256 threads, tile 64 rows x 64 cols, K=128 resident in LDS
__global__ __launch_bounds__(256) void gemm128(
    const float* __restrict__ A, int M,
    const float* __restrict__ W, const float* __restrict__ bias,
    float* __restrict__ C)
{
  __shared__ float xsT[128][68];  // [k][r], +4 pad keeps 16B align & breaks write conflicts
  __shared__ float ws[128][64];   // [k][c]
  const int tid = threadIdx.x;
  const int row0 = blockIdx.x * 64;
  const int col0 = blockIdx.y * 64;

#pragma unroll
  for (int i = 0; i < 8; ++i) {          // stage W slice 128x64
    int f = tid + i * 256;
    int k = f >> 4;
    int c4 = (f & 15) << 2;
    *(float4*)(&ws[k][c4]) = *(const float4*)(W + k * 128 + col0 + c4);
  }
#pragma unroll
  for (int i = 0; i < 8; ++i) {          // stage A tile 64x128, transposed
    int f = tid + i * 256;
    int r = f >> 5;
    int kk = (f & 31) << 2;
    int gr = row0 + r;
    float4 v = make_float4(0.f, 0.f, 0.f, 0.f);
    if (gr < M) v = *(const float4*)(A + (size_t)gr * 128 + kk);
    xsT[kk + 0][r] = v.x; xsT[kk + 1][r] = v.y; xsT[kk + 2][r] = v.z; xsT[kk + 3][r] = v.w;
  }
  __syncthreads();

  const int tx = tid & 15, ty = tid >> 4;
  float acc[4][4] = {};
#pragma unroll 8
  for (int k = 0; k < 128; ++k) {
    float4 xv = *(const float4*)(&xsT[k][ty << 2]);
    float4 wv = *(const float4*)(&ws[k][tx << 2]);
    acc[0][0] = fmaf(xv.x, wv.x, acc[0][0]);
    acc[0][1] = fmaf(xv.x, wv.y, acc[0][1]);
    acc[0][2] = fmaf(xv.x, wv.z, acc[0][2]);
    acc[0][3] = fmaf(xv.x, wv.w, acc[0][3]);
    acc[1][0] = fmaf(xv.y, wv.x, acc[1][0]);
    acc[1][1] = fmaf(xv.y, wv.y, acc[1][1]);
    acc[1][2] = fmaf(xv.y, wv.z, acc[1][2]);
    acc[1][3] = fmaf(xv.y, wv.w, acc[1][3]);
    acc[2][0] = fmaf(xv.z, wv.x, acc[2][0]);
    acc[2][1] = fmaf(xv.z, wv.y, acc[2][1]);
    acc[2][2] = fmaf(xv.z, wv.z, acc[2][2]);
    acc[2][3] = fmaf(xv.z, wv.w, acc[2][3]);
    acc[3][0] = fmaf(xv.w, wv.x, acc[3][0]);
    acc[3][1] = fmaf(xv.w, wv.y, acc[3][1]);
    acc[3][2] = fmaf(xv.w, wv.z, acc[3][2]);
    acc[3][3] = fmaf(xv.w, wv.w, acc[3][3]);
  }

  const int gc = col0 + (tx << 2);
  float4 b4 = *(const float4*)(bias + gc);
#pragma unroll
  for (int i = 0; i < 4; ++i) {
    int gr = row0 + (ty << 2) + i;
    if (gr < M) {
      float4 o = make_float4(acc[i][0] + b4.x, acc[i][1] + b4.y,
                             acc[i][2] + b4.z, acc[i][3] + b4.w);
      *(float4*)(C + (size_t)gr * 128 + gc) = o;
    }
  }
}

// ---------------- edge-weight denominator: den[dst] += max(ew,0) ----------------
__global__ __launch_bounds__(256) void edge_den(
    const float* __restrict__ ew, const int* __restrict__ dst,
    float* __restrict__ den, int E)
{
  int e = blockIdx.x * 256 + threadIdx.x;
  if (e < E) atomicAdd(&den[dst[e]], fmaxf(ew[e], 0.f));
}

// ---------------- per-(edge,head) logits -> exp, accumulate softmax denom ----------------
__global__ __launch_bounds__(256) void edge_logits(
    const float* __restrict__ q, const float* __restrict__ khat,
    const int* __restrict__ src, const int* __restrict__ dst,
    const float* __restrict__ ew, const float* __restrict__ den,
    const float* __restrict__ pri,
    float* __restrict__ evv, float* __restrict__ s, int E)
{
  int gid = blockIdx.x * 256 + threadIdx.x;
  int e = gid >> 3, h = gid & 7;
  if (e >= E) return;
  int si = src[e], di = dst[e];
  const float4* qp = (const float4*)(q + (size_t)di * 128 + h * 16);
  const float4* kp = (const float4*)(khat + (size_t)si * 128 + h * 16);
  float t = 0.f;
#pragma unroll
  for (int u = 0; u < 4; ++u) {
    float4 a = qp[u], b = kp[u];
    t = fmaf(a.x, b.x, fmaf(a.y, b.y, fmaf(a.z, b.z, fmaf(a.w, b.w, t))));
  }
  float wv = fmaxf(ew[e], 0.f);
  float dv = fmaxf(den[di], EPSF);
  float lg = logf(wv / dv + EPSF);
  float tt = (t + lg) * pri[h] * 0.25f;   // /sqrt(DK)=1/4
  // logits bounded in [~-5.4, ~0.3] -> exp without segment-max is safe
  float x = expf(tt);
  evv[(size_t)e * 8 + h] = x;
  atomicAdd(&s[(size_t)di * 8 + h], x);
}

// ---------------- aggregate messages: agg[dst] += vhat[src] * a ----------------
__global__ __launch_bounds__(256) void edge_agg(
    const float* __restrict__ vhat,
    const int* __restrict__ src, const int* __restrict__ dst,
    const float* __restrict__ evv, const float* __restrict__ s,
    float* __restrict__ agg, int E)
{
  int gid = blockIdx.x * 256 + threadIdx.x;
  int e = gid >> 3, h = gid & 7;
  if (e >= E) return;
  int si = src[e], di = dst[e];
  float a = evv[(size_t)e * 8 + h] / s[(size_t)di * 8 + h];
  const float4* vp = (const float4*)(vhat + (size_t)si * 128 + h * 16);
  float* ap = agg + (size_t)di * 128 + h * 16;
#pragma unroll
  for (int u = 0; u < 4; ++u) {
    float4 v = vp[u];
    atomicAdd(ap + u * 4 + 0, v.x * a);
    atomicAdd(ap + u * 4 + 1, v.y * a);
    atomicAdd(ap + u * 4 + 2, v.z * a);
    atomicAdd(ap + u * 4 + 3, v.w * a);
  }
}

// ---------------- skip-mix + LayerNorm epilogue, one wave per row ----------------
__global__ __launch_bounds__(256) void ln_final(
    const float* __restrict__ tra, const float* __restrict__ trb,
    const float* __restrict__ xa, const float* __restrict__ xb,
    const float* __restrict__ g, const float* __restrict__ bta,
    const float* __restrict__ skip,
    float* __restrict__ out, int NA, int NB)
{
  int wid = (blockIdx.x * 256 + threadIdx.x) >> 6;
  int lane = threadIdx.x & 63;
  if (wid >= NA + NB) return;
  int t; const float *tr, *bs;
  if (wid < NA) { t = 0; tr = tra + (size_t)wid * 128; bs = xa + (size_t)wid * 128; }
  else { t = 1; int r = wid - NA; tr = trb + (size_t)r * 128; bs = xb + (size_t)r * 128; }
  float* o = out + (size_t)wid * 128;
  float alpha = 1.f / (1.f + expf(-skip[t]));
  float2 tv = *(const float2*)(tr + lane * 2);
  float2 xv = *(const float2*)(bs + lane * 2);
  float o0 = tv.x * alpha + xv.x * (1.f - alpha);
  float o1 = tv.y * alpha + xv.y * (1.f - alpha);
  float sm = o0 + o1;
#pragma unroll
  for (int m = 32; m; m >>= 1) sm += __shfl_xor(sm, m, 64);
  float mu = sm * (1.f / 128.f);
  float d0 = o0 - mu, d1 = o1 - mu;
  float vv = d0 * d0 + d1 * d1;
#pragma unroll
  for (int m = 32; m; m >>= 1) vv += __shfl_xor(vv, m, 64);
  float inv = 1.f / sqrtf(vv * (1.f / 128.f) + 1e-5f);
  int c = lane * 2;
  o[c]     = d0 * inv * g[t * 128 + c]     + bta[t * 128 + c];
  o[c + 1] = d1 * inv * g[t * 128 + c + 1] + bta[t * 128 + c + 1];
}

// ---------------- launch ----------------
extern "C" void kernel_launch(void* const* d_in, const int* in_sizes, int n_in,
                              void* d_out, int out_size, void* d_ws, size_t ws_size,
                              hipStream_t stream)
{
  const float* x_a = (const float*)d_in[0];
  const float* x_b = (const float*)d_in[1];
  const float* ew0 = (const float*)d_in[2];
  const float* ew1 = (const float*)d_in[3];
  const int* src0 = (const int*)d_in[4];
  const int* dst0 = (const int*)d_in[5];
  const int* src1 = (const int*)d_in[6];
  const int* dst1 = (const int*)d_in[7];
  const float* Wk = (const float*)d_in[8];
  const float* bk = (const float*)d_in[9];
  const float* Wq = (const float*)d_in[10];
  const float* bq = (const float*)d_in[11];
  const float* Wv = (const float*)d_in[12];
  const float* bv = (const float*)d_in[13];
  const float* Wa = (const float*)d_in[14];
  const float* ba = (const float*)d_in[15];
  const float* ln_g = (const float*)d_in[16];
  const float* ln_b = (const float*)d_in[17];
  const float* rel_pri = (const float*)d_in[18];
  const float* rel_att = (const float*)d_in[19];
  const float* rel_msg = (const float*)d_in[20];
  const float* skip = (const float*)d_in[21];

  int NA = in_sizes[0] / 128, NB = in_sizes[1] / 128;
  int E0 = in_sizes[2], E1 = in_sizes[3];
  int NMAX = NA > NB ? NA : NB;
  int EMAX = E0 > E1 ? E0 : E1;

  float* w = (float*)d_ws;
  float* khat = w;                               // NMAX*128  (also reused as trans_a)
  float* vhat = khat + (size_t)NMAX * 128;       // NMAX*128  (also reused as trans_b)
  float* qd   = vhat + (size_t)NMAX * 128;       // NMAX*128
  float* evv  = qd   + (size_t)NMAX * 128;       // EMAX*8
  float* s_   = evv  + (size_t)EMAX * 8;         // NMAX*8
  float* den_ = s_   + (size_t)NMAX * 8;         // NMAX     (contiguous with s_ for zeroing)
  float* Wkf  = den_ + NMAX;                     // 2*128*128
  float* Wvf  = Wkf + 2 * 128 * 128;
  float* bkf  = Wvf + 2 * 128 * 128;             // 2*128
  float* bvf  = bkf + 2 * 128;

  float* outf = (float*)d_out;
  float* agg_a = outf;                           // d_out doubles as the message accumulator
  float* agg_b = outf + (size_t)NA * 128;

  dim3 b256(256);
  auto gg = [](int M) { return dim3((unsigned)((M + 63) / 64), 2); };

  fzero<<<2048, b256, 0, stream>>>(outf, (long)(NA + NB) * 128);
  fuse_w<<<dim3(129, 2, 2), 128, 0, stream>>>(Wk, bk, Wv, bv, rel_att, rel_msg,
                                              Wkf, bkf, Wvf, bvf);

  // ---- relation 0: a -> b (k/v from a w/ rel0-fused W, q from b) ----
  gemm128<<<gg(NA), b256, 0, stream>>>(x_a, NA, Wkf, bkf, khat);
  gemm128<<<gg(NA), b256, 0, stream>>>(x_a, NA, Wvf, bvf, vhat);
  gemm128<<<gg(NB), b256, 0, stream>>>(x_b, NB, Wq + 16384, bq + 128, qd);
  fzero<<<512, b256, 0, stream>>>(s_, (long)NMAX * 8 + NMAX);
  edge_den<<<(E0 + 255) / 256, b256, 0, stream>>>(ew0, dst0, den_, E0);
  edge_logits<<<(unsigned)(((size_t)E0 * 8 + 255) / 256), b256, 0, stream>>>(
      qd, khat, src0, dst0, ew0, den_, rel_pri, evv, s_, E0);
  edge_agg<<<(unsigned)(((size_t)E0 * 8 + 255) / 256), b256, 0, stream>>>(
      vhat, src0, dst0, evv, s_, agg_b, E0);

  // ---- relation 1: b -> a ----
  gemm128<<<gg(NB), b256, 0, stream>>>(x_b, NB, Wkf + 16384, bkf + 128, khat);
  gemm128<<<gg(NB), b256, 0, stream>>>(x_b, NB, Wvf + 16384, bvf + 128, vhat);
  gemm128<<<gg(NA), b256, 0, stream>>>(x_a, NA, Wq, bq, qd);
  fzero<<<512, b256, 0, stream>>>(s_, (long)NMAX * 8 + NMAX);
  edge_den<<<(E1 + 255) / 256, b256, 0, stream>>>(ew1, dst1, den_, E1);
  edge_logits<<<(unsigned)(((size_t)E1 * 8 + 255) / 256), b256, 0, stream>>>(
      qd, khat, src1, dst1, ew1, den_, rel_pri + 8, evv, s_, E1);
  edge_agg<<<(unsigned)(((size_t)E1 * 8 + 255) / 256), b256, 0, stream>>>(
      vhat, src1, dst1, evv, s_, agg_a, E1);

  // ---- output projection (trans = agg @ Wa + ba), reuse khat/vhat as tmp ----
  gemm128<<<gg(NA), b256, 0, stream>>>(agg_a, NA, Wa, ba, khat);
  gemm128<<<gg(NB), b256, 0, stream>>>(agg_b, NB, Wa + 16384, ba + 128, vhat);

  int rows = NA + NB;
  ln_final<<<(rows + 3) / 4, b256, 0, stream>>>(khat, vhat, x_a, x_b,
                                                ln_g, ln_b, skip, outf, NA, NB);
}

// Round 2
// 1127.333 us; speedup vs baseline: 6.0057x; 6.0057x over previous
//
#include <hip/hip_runtime.h>
#include <cstdint>
#include <cstddef>

#define EPSF 1e-9f

// ---------------- zero ----------------
__global__ __launch_bounds__(256) void fzero(float* __restrict__ p, long n) {
  long i = (long)blockIdx.x * blockDim.x + threadIdx.x;
  long stride = (long)gridDim.x * blockDim.x;
  long n4 = n >> 2;
  float4* p4 = (float4*)p;
  for (long j = i; j < n4; j += stride) p4[j] = make_float4(0.f, 0.f, 0.f, 0.f);
  for (long j = (n4 << 2) + i; j < n; j += stride) p[j] = 0.f;
}

// ---------------- fold rel_att/rel_msg into W ----------------
__global__ __launch_bounds__(128) void fuse_w(
    const float* __restrict__ Wk, const float* __restrict__ bk,
    const float* __restrict__ Wv, const float* __restrict__ bv,
    const float* __restrict__ rel_att, const float* __restrict__ rel_msg,
    float* __restrict__ Wkf, float* __restrict__ bkf,
    float* __restrict__ Wvf, float* __restrict__ bvf)
{
  int i = blockIdx.x;   // 0..128 (128 == bias)
  int t = blockIdx.y;   // node type
  int m = blockIdx.z;   // 0=k path, 1=v path
  int c = threadIdx.x;  // output col
  int h = c >> 4, e = c & 15;
  const float* R = (m ? rel_msg : rel_att) + t * 2048 + h * 256;
  const float* srcW = (m ? Wv : Wk) + t * 16384;
  const float* srcB = (m ? bv : bk) + t * 128;
  const float* row = (i < 128) ? (srcW + i * 128) : srcB;
  float acc = 0.f;
#pragma unroll
  for (int d = 0; d < 16; ++d) acc = fmaf(row[h * 16 + d], R[d * 16 + e], acc);
  if (i < 128) (m ? Wvf : Wkf)[t * 16384 + i * 128 + c] = acc;
  else         (m ? bvf : bkf)[t * 128 + c] = acc;
}

// ---------------- f32 GEMM: C = A[Mx128] @ W[128x128] + bias ----------------
__global__ __launch_bounds__(256) void gemm128(
    const float* __restrict__ A, int M,
    const float* __restrict__ W, const float* __restrict__ bias,
    float* __restrict__ C)
{
  __shared__ float xsT[128][68];
  __shared__ float ws[128][64];
  const int tid = threadIdx.x;
  const int row0 = blockIdx.x * 64;
  const int col0 = blockIdx.y * 64;

#pragma unroll
  for (int i = 0; i < 8; ++i) {
    int f = tid + i * 256;
    int k = f >> 4;
    int c4 = (f & 15) << 2;
    *(float4*)(&ws[k][c4]) = *(const float4*)(W + k * 128 + col0 + c4);
  }
#pragma unroll
  for (int i = 0; i < 8; ++i) {
    int f = tid + i * 256;
    int r = f >> 5;
    int kk = (f & 31) << 2;
    int gr = row0 + r;
    float4 v = make_float4(0.f, 0.f, 0.f, 0.f);
    if (gr < M) v = *(const float4*)(A + (size_t)gr * 128 + kk);
    xsT[kk + 0][r] = v.x; xsT[kk + 1][r] = v.y; xsT[kk + 2][r] = v.z; xsT[kk + 3][r] = v.w;
  }
  __syncthreads();

  const int tx = tid & 15, ty = tid >> 4;
  float acc[4][4] = {};
#pragma unroll 8
  for (int k = 0; k < 128; ++k) {
    float4 xv = *(const float4*)(&xsT[k][ty << 2]);
    float4 wv = *(const float4*)(&ws[k][tx << 2]);
    acc[0][0] = fmaf(xv.x, wv.x, acc[0][0]);
    acc[0][1] = fmaf(xv.x, wv.y, acc[0][1]);
    acc[0][2] = fmaf(xv.x, wv.z, acc[0][2]);
    acc[0][3] = fmaf(xv.x, wv.w, acc[0][3]);
    acc[1][0] = fmaf(xv.y, wv.x, acc[1][0]);
    acc[1][1] = fmaf(xv.y, wv.y, acc[1][1]);
    acc[1][2] = fmaf(xv.y, wv.z, acc[1][2]);
    acc[1][3] = fmaf(xv.y, wv.w, acc[1][3]);
    acc[2][0] = fmaf(xv.z, wv.x, acc[2][0]);
    acc[2][1] = fmaf(xv.z, wv.y, acc[2][1]);
    acc[2][2] = fmaf(xv.z, wv.z, acc[2][2]);
    acc[2][3] = fmaf(xv.z, wv.w, acc[2][3]);
    acc[3][0] = fmaf(xv.w, wv.x, acc[3][0]);
    acc[3][1] = fmaf(xv.w, wv.y, acc[3][1]);
    acc[3][2] = fmaf(xv.w, wv.z, acc[3][2]);
    acc[3][3] = fmaf(xv.w, wv.w, acc[3][3]);
  }

  const int gc = col0 + (tx << 2);
  float4 b4 = *(const float4*)(bias + gc);
#pragma unroll
  for (int i = 0; i < 4; ++i) {
    int gr = row0 + (ty << 2) + i;
    if (gr < M) {
      float4 o = make_float4(acc[i][0] + b4.x, acc[i][1] + b4.y,
                             acc[i][2] + b4.z, acc[i][3] + b4.w);
      *(float4*)(C + (size_t)gr * 128 + gc) = o;
    }
  }
}

// ---------------- CSR build ----------------
__global__ __launch_bounds__(256) void csr_count(
    const int* __restrict__ dst, int* __restrict__ deg, int E)
{
  int e = blockIdx.x * 256 + threadIdx.x;
  if (e < E) atomicAdd(&deg[dst[e]], 1);
}

// per-block (1024-elem chunk) partial sums
__global__ __launch_bounds__(256) void csr_partial(
    const int* __restrict__ deg, int N, int* __restrict__ partial)
{
  int base = blockIdx.x * 1024 + threadIdx.x * 4;
  int s = 0;
#pragma unroll
  for (int i = 0; i < 4; ++i) if (base + i < N) s += deg[base + i];
#pragma unroll
  for (int m = 1; m < 64; m <<= 1) s += __shfl_xor(s, m, 64);
  __shared__ int wsum[4];
  if ((threadIdx.x & 63) == 0) wsum[threadIdx.x >> 6] = s;
  __syncthreads();
  if (threadIdx.x == 0) partial[blockIdx.x] = wsum[0] + wsum[1] + wsum[2] + wsum[3];
}

__global__ void csr_scan_partials(const int* __restrict__ partial,
                                  int* __restrict__ pscan, int NP)
{
  if (blockIdx.x == 0 && threadIdx.x == 0) {
    int s = 0;
    for (int i = 0; i < NP; ++i) { pscan[i] = s; s += partial[i]; }
  }
}

// exclusive scan within each 1024 chunk + chunk offset -> row_start, cursor
__global__ __launch_bounds__(256) void csr_scan_chunk(
    const int* __restrict__ deg, const int* __restrict__ pscan,
    int* __restrict__ row_start, int* __restrict__ cursor, int N)
{
  __shared__ int ls[256];
  int base = blockIdx.x * 1024 + threadIdx.x * 4;
  int v0 = 0, v1 = 0, v2 = 0, v3 = 0;
  if (base + 0 < N) v0 = deg[base + 0];
  if (base + 1 < N) v1 = deg[base + 1];
  if (base + 2 < N) v2 = deg[base + 2];
  if (base + 3 < N) v3 = deg[base + 3];
  int s = v0 + v1 + v2 + v3;
  ls[threadIdx.x] = s;
  __syncthreads();
  for (int off = 1; off < 256; off <<= 1) {
    int t = (threadIdx.x >= off) ? ls[threadIdx.x - off] : 0;
    __syncthreads();
    ls[threadIdx.x] += t;
    __syncthreads();
  }
  int excl = pscan[blockIdx.x] + ls[threadIdx.x] - s;
  int p0 = excl, p1 = excl + v0, p2 = excl + v0 + v1, p3 = excl + v0 + v1 + v2;
  if (base + 0 < N) { row_start[base + 0] = p0; cursor[base + 0] = p0; }
  if (base + 1 < N) { row_start[base + 1] = p1; cursor[base + 1] = p1; }
  if (base + 2 < N) { row_start[base + 2] = p2; cursor[base + 2] = p2; }
  if (base + 3 < N) { row_start[base + 3] = p3; cursor[base + 3] = p3; }
}

__global__ __launch_bounds__(256) void csr_scatter(
    const int* __restrict__ dst, int* __restrict__ cursor,
    int* __restrict__ eidx, int E)
{
  int e = blockIdx.x * 256 + threadIdx.x;
  if (e < E) {
    int p = atomicAdd(&cursor[dst[e]], 1);
    eidx[p] = e;
  }
}

// ---------------- fused per-dst attention: den + logits + softmax + aggregate ----------------
// one 64-lane wave per dst node; lane owns 2 output dims; 8 lanes = 1 head
__global__ __launch_bounds__(256) void hgt_dst(
    const float* __restrict__ q, const float* __restrict__ khat,
    const float* __restrict__ vhat,
    const int* __restrict__ src, const float* __restrict__ ew,
    const int* __restrict__ row_start, const int* __restrict__ deg,
    const int* __restrict__ eidx, const float* __restrict__ pri8,
    float* __restrict__ agg, int N)
{
  int n = (blockIdx.x * 256 + threadIdx.x) >> 6;
  int lane = threadIdx.x & 63;
  if (n >= N) return;
  int c0 = lane * 2;
  float* out = agg + (size_t)n * 128;
  int d = deg[n];
  if (d == 0) { *(float2*)(out + c0) = make_float2(0.f, 0.f); return; }
  int base = row_start[n];

  // edge-weight denominator for this dst
  float ds = 0.f;
  for (int j = lane; j < d; j += 64) ds += fmaxf(ew[eidx[base + j]], 0.f);
#pragma unroll
  for (int m = 1; m < 64; m <<= 1) ds += __shfl_xor(ds, m, 64);
  float inv_den = 1.f / fmaxf(ds, EPSF);

  int h = lane >> 3;
  float pr = pri8[h] * 0.25f;  // pri / sqrt(DK)
  float2 qv = *(const float2*)(q + (size_t)n * 128 + c0);

  float s = 0.f;
  float2 acc = make_float2(0.f, 0.f);
  for (int j = 0; j < d; ++j) {
    int ei = eidx[base + j];
    int si = src[ei];
    float2 kv = *(const float2*)(khat + (size_t)si * 128 + c0);
    float t = qv.x * kv.x + qv.y * kv.y;
    t += __shfl_xor(t, 1, 64);
    t += __shfl_xor(t, 2, 64);
    t += __shfl_xor(t, 4, 64);   // per-head 16-dim dot, broadcast in 8-lane group
    float wv = fmaxf(ew[ei], 0.f);
    float lg = logf(wv * inv_den + EPSF);
    // logits bounded (|dot|<~2, lg in [-20.7, 0]) * pri*0.25 -> exp safe w/o max pass
    float x = expf((t + lg) * pr);
    s += x;
    float2 vv = *(const float2*)(vhat + (size_t)si * 128 + c0);
    acc.x = fmaf(x, vv.x, acc.x);
    acc.y = fmaf(x, vv.y, acc.y);
  }
  float is = 1.f / s;
  *(float2*)(out + c0) = make_float2(acc.x * is, acc.y * is);
}

// ---------------- skip-mix + LayerNorm epilogue, one wave per row ----------------
__global__ __launch_bounds__(256) void ln_final(
    const float* __restrict__ tra, const float* __restrict__ trb,
    const float* __restrict__ xa, const float* __restrict__ xb,
    const float* __restrict__ g, const float* __restrict__ bta,
    const float* __restrict__ skip,
    float* __restrict__ out, int NA, int NB)
{
  int wid = (blockIdx.x * 256 + threadIdx.x) >> 6;
  int lane = threadIdx.x & 63;
  if (wid >= NA + NB) return;
  int t; const float *tr, *bs;
  if (wid < NA) { t = 0; tr = tra + (size_t)wid * 128; bs = xa + (size_t)wid * 128; }
  else { t = 1; int r = wid - NA; tr = trb + (size_t)r * 128; bs = xb + (size_t)r * 128; }
  float* o = out + (size_t)wid * 128;
  float alpha = 1.f / (1.f + expf(-skip[t]));
  float2 tv = *(const float2*)(tr + lane * 2);
  float2 xv = *(const float2*)(bs + lane * 2);
  float o0 = tv.x * alpha + xv.x * (1.f - alpha);
  float o1 = tv.y * alpha + xv.y * (1.f - alpha);
  float sm = o0 + o1;
#pragma unroll
  for (int m = 32; m; m >>= 1) sm += __shfl_xor(sm, m, 64);
  float mu = sm * (1.f / 128.f);
  float d0 = o0 - mu, d1 = o1 - mu;
  float vv = d0 * d0 + d1 * d1;
#pragma unroll
  for (int m = 32; m; m >>= 1) vv += __shfl_xor(vv, m, 64);
  float inv = 1.f / sqrtf(vv * (1.f / 128.f) + 1e-5f);
  int c = lane * 2;
  o[c]     = d0 * inv * g[t * 128 + c]     + bta[t * 128 + c];
  o[c + 1] = d1 * inv * g[t * 128 + c + 1] + bta[t * 128 + c + 1];
}

// ---------------- launch ----------------
extern "C" void kernel_launch(void* const* d_in, const int* in_sizes, int n_in,
                              void* d_out, int out_size, void* d_ws, size_t ws_size,
                              hipStream_t stream)
{
  const float* x_a = (const float*)d_in[0];
  const float* x_b = (const float*)d_in[1];
  const float* ew0 = (const float*)d_in[2];
  const float* ew1 = (const float*)d_in[3];
  const int* src0 = (const int*)d_in[4];
  const int* dst0 = (const int*)d_in[5];
  const int* src1 = (const int*)d_in[6];
  const int* dst1 = (const int*)d_in[7];
  const float* Wk = (const float*)d_in[8];
  const float* bk = (const float*)d_in[9];
  const float* Wq = (const float*)d_in[10];
  const float* bq = (const float*)d_in[11];
  const float* Wv = (const float*)d_in[12];
  const float* bv = (const float*)d_in[13];
  const float* Wa = (const float*)d_in[14];
  const float* ba = (const float*)d_in[15];
  const float* ln_g = (const float*)d_in[16];
  const float* ln_b = (const float*)d_in[17];
  const float* rel_pri = (const float*)d_in[18];
  const float* rel_att = (const float*)d_in[19];
  const float* rel_msg = (const float*)d_in[20];
  const float* skip = (const float*)d_in[21];

  int NA = in_sizes[0] / 128, NB = in_sizes[1] / 128;
  int E0 = in_sizes[2], E1 = in_sizes[3];
  int NMAX = NA > NB ? NA : NB;
  int EMAX = E0 > E1 ? E0 : E1;
  int NM = (NMAX + 255) & ~255;   // aligned layout stride
  int EM = (EMAX + 255) & ~255;

  float* w = (float*)d_ws;
  float* khat = w;                               // NM*128
  float* vhat = khat + (size_t)NM * 128;         // NM*128
  float* qd   = vhat + (size_t)NM * 128;         // NM*128
  float* Wkf  = qd   + (size_t)NM * 128;         // 2*16384
  float* Wvf  = Wkf + 2 * 16384;
  float* bkf  = Wvf + 2 * 16384;                 // 256
  float* bvf  = bkf + 256;
  int* deg     = (int*)(bvf + 256);              // NM
  int* row_st  = deg + NM;                       // NM
  int* cursor  = row_st + NM;                    // NM
  int* eidx    = cursor + NM;                    // EM
  int* partial = eidx + EM;                      // 1024
  int* pscan   = partial + 1024;                 // 1024

  float* outf = (float*)d_out;
  float* agg_a = outf;                           // d_out doubles as agg buffer
  float* agg_b = outf + (size_t)NA * 128;

  dim3 b256(256);
  auto gg = [](int M) { return dim3((unsigned)((M + 63) / 64), 2); };
  auto csr_build = [&](const int* dstp, int E, int N) {
    int NP = (N + 1023) / 1024;
    fzero<<<256, b256, 0, stream>>>((float*)deg, N);
    csr_count<<<(E + 255) / 256, b256, 0, stream>>>(dstp, deg, E);
    csr_partial<<<NP, b256, 0, stream>>>(deg, N, partial);
    csr_scan_partials<<<1, 64, 0, stream>>>(partial, pscan, NP);
    csr_scan_chunk<<<NP, b256, 0, stream>>>(deg, pscan, row_st, cursor, N);
    csr_scatter<<<(E + 255) / 256, b256, 0, stream>>>(dstp, cursor, eidx, E);
  };

  fuse_w<<<dim3(129, 2, 2), 128, 0, stream>>>(Wk, bk, Wv, bv, rel_att, rel_msg,
                                              Wkf, bkf, Wvf, bvf);

  // ---- relation 0: a -> b ----
  gemm128<<<gg(NA), b256, 0, stream>>>(x_a, NA, Wkf, bkf, khat);
  gemm128<<<gg(NA), b256, 0, stream>>>(x_a, NA, Wvf, bvf, vhat);
  gemm128<<<gg(NB), b256, 0, stream>>>(x_b, NB, Wq + 16384, bq + 128, qd);
  csr_build(dst0, E0, NB);
  hgt_dst<<<(NB + 3) / 4, b256, 0, stream>>>(qd, khat, vhat, src0, ew0,
                                             row_st, deg, eidx, rel_pri, agg_b, NB);

  // ---- relation 1: b -> a ----
  gemm128<<<gg(NB), b256, 0, stream>>>(x_b, NB, Wkf + 16384, bkf + 128, khat);
  gemm128<<<gg(NB), b256, 0, stream>>>(x_b, NB, Wvf + 16384, bvf + 128, vhat);
  gemm128<<<gg(NA), b256, 0, stream>>>(x_a, NA, Wq, bq, qd);
  csr_build(dst1, E1, NA);
  hgt_dst<<<(NA + 3) / 4, b256, 0, stream>>>(qd, khat, vhat, src1, ew1,
                                             row_st, deg, eidx, rel_pri + 8, agg_a, NA);

  // ---- output projection (trans = agg @ Wa + ba), reuse khat/vhat ----
  gemm128<<<gg(NA), b256, 0, stream>>>(agg_a, NA, Wa, ba, khat);
  gemm128<<<gg(NB), b256, 0, stream>>>(agg_b, NB, Wa + 16384, ba + 128, vhat);

  int rows = NA + NB;
  ln_final<<<(rows + 3) / 4, b256, 0, stream>>>(khat, vhat, x_a, x_b,
                                                ln_g, ln_b, skip, outf, NA, NB);
}

// Round 5
// 965.049 us; speedup vs baseline: 7.0156x; 1.1682x over previous
//
#include <hip/hip_runtime.h>
#include <cstdint>
#include <cstddef>

#define EPSF 1e-9f

// ---------------- zero ----------------
__global__ __launch_bounds__(256) void fzero(float* __restrict__ p, long n) {
  long i = (long)blockIdx.x * blockDim.x + threadIdx.x;
  long stride = (long)gridDim.x * blockDim.x;
  long n4 = n >> 2;
  float4* p4 = (float4*)p;
  for (long j = i; j < n4; j += stride) p4[j] = make_float4(0.f, 0.f, 0.f, 0.f);
  for (long j = (n4 << 2) + i; j < n; j += stride) p[j] = 0.f;
}

// ---------------- fold rel_att/rel_msg into W, concat [K|V] -> 128x256 ----------------
__global__ __launch_bounds__(256) void fuse_w(
    const float* __restrict__ Wk, const float* __restrict__ bk,
    const float* __restrict__ Wv, const float* __restrict__ bv,
    const float* __restrict__ rel_att, const float* __restrict__ rel_msg,
    float* __restrict__ Wkvf, float* __restrict__ bkvf)
{
  int i = blockIdx.x;   // 0..128 (128 == bias row)
  int t = blockIdx.y;   // node type (= relation where this type is src)
  int c = threadIdx.x;  // 0..255: [0,128)=k cols, [128,256)=v cols
  int m = c >> 7, cc = c & 127;
  int h = cc >> 4, e = cc & 15;
  const float* R = (m ? rel_msg : rel_att) + t * 2048 + h * 256;
  const float* srcW = (m ? Wv : Wk) + t * 16384;
  const float* srcB = (m ? bv : bk) + t * 128;
  const float* row = (i < 128) ? (srcW + i * 128) : srcB;
  float acc = 0.f;
#pragma unroll
  for (int d = 0; d < 16; ++d) acc = fmaf(row[h * 16 + d], R[d * 16 + e], acc);
  if (i < 128) Wkvf[t * 32768 + i * 256 + c] = acc;
  else         bkvf[t * 256 + c] = acc;
}

// ---------------- f32 GEMM: C[64r x 128c tile] = A[Mx128] @ W[128 x ldw] + bias ----------------
// 256 thr; thread = 4 rows x (4+4) cols (col-pair split keeps LDS read 2-way/free);
// W staged in two 64-k chunks -> LDS 67KB -> 2 blocks/CU.
__global__ __launch_bounds__(256) void gemm_tile(
    const float* __restrict__ A, int M,
    const float* __restrict__ W, int ldw, const float* __restrict__ bias,
    float* __restrict__ C, int ldc)
{
  __shared__ float xsT[128][68];   // [k][row]
  __shared__ float ws[64][128];    // [k-chunk][col]
  const int tid = threadIdx.x;
  const int row0 = blockIdx.x * 64;
  const int col0 = blockIdx.y * 128;

#pragma unroll
  for (int i = 0; i < 8; ++i) {          // stage A 64r x 128k transposed
    int f = tid + i * 256;
    int r = f >> 5;
    int kk = (f & 31) << 2;
    int gr = row0 + r;
    float4 v = make_float4(0.f, 0.f, 0.f, 0.f);
    if (gr < M) v = *(const float4*)(A + (size_t)gr * 128 + kk);
    xsT[kk + 0][r] = v.x; xsT[kk + 1][r] = v.y; xsT[kk + 2][r] = v.z; xsT[kk + 3][r] = v.w;
  }

  const int tx = tid & 15, ty = tid >> 4;
  const int cA = tx * 4, cB = 64 + tx * 4;
  float acc[4][8] = {};

  for (int kc = 0; kc < 128; kc += 64) {
    __syncthreads();                     // ws free of prior readers (and A staged, iter 0)
#pragma unroll
    for (int i = 0; i < 8; ++i) {        // stage W chunk 64k x 128c
      int f = tid + i * 256;
      int k = f >> 5;
      int c4 = (f & 31) << 2;
      *(float4*)(&ws[k][c4]) = *(const float4*)(W + (size_t)(kc + k) * ldw + col0 + c4);
    }
    __syncthreads();
#pragma unroll 4
    for (int k = 0; k < 64; ++k) {
      float4 xv = *(const float4*)(&xsT[kc + k][ty << 2]);
      float4 wa = *(const float4*)(&ws[k][cA]);
      float4 wb = *(const float4*)(&ws[k][cB]);
#define FMA_ROW(r, xs) \
      acc[r][0] = fmaf(xs, wa.x, acc[r][0]); \
      acc[r][1] = fmaf(xs, wa.y, acc[r][1]); \
      acc[r][2] = fmaf(xs, wa.z, acc[r][2]); \
      acc[r][3] = fmaf(xs, wa.w, acc[r][3]); \
      acc[r][4] = fmaf(xs, wb.x, acc[r][4]); \
      acc[r][5] = fmaf(xs, wb.y, acc[r][5]); \
      acc[r][6] = fmaf(xs, wb.z, acc[r][6]); \
      acc[r][7] = fmaf(xs, wb.w, acc[r][7]);
      FMA_ROW(0, xv.x) FMA_ROW(1, xv.y) FMA_ROW(2, xv.z) FMA_ROW(3, xv.w)
#undef FMA_ROW
    }
  }

  float4 bA = *(const float4*)(bias + col0 + cA);
  float4 bB = *(const float4*)(bias + col0 + cB);
#pragma unroll
  for (int i = 0; i < 4; ++i) {
    int gr = row0 + (ty << 2) + i;
    if (gr < M) {
      float4 oA = make_float4(acc[i][0] + bA.x, acc[i][1] + bA.y,
                              acc[i][2] + bA.z, acc[i][3] + bA.w);
      float4 oB = make_float4(acc[i][4] + bB.x, acc[i][5] + bB.y,
                              acc[i][6] + bB.z, acc[i][7] + bB.w);
      *(float4*)(C + (size_t)gr * ldc + col0 + cA) = oA;
      *(float4*)(C + (size_t)gr * ldc + col0 + cB) = oB;
    }
  }
}

// ---------------- CSR build ----------------
__global__ __launch_bounds__(256) void csr_count(
    const int* __restrict__ dst, int* __restrict__ deg, int E)
{
  int e = blockIdx.x * 256 + threadIdx.x;
  if (e < E) atomicAdd(&deg[dst[e]], 1);
}

__global__ __launch_bounds__(256) void csr_partial(
    const int* __restrict__ deg, int N, int* __restrict__ partial)
{
  int base = blockIdx.x * 1024 + threadIdx.x * 4;
  int s = 0;
#pragma unroll
  for (int i = 0; i < 4; ++i) if (base + i < N) s += deg[base + i];
#pragma unroll
  for (int m = 1; m < 64; m <<= 1) s += __shfl_xor(s, m, 64);
  __shared__ int wsum[4];
  if ((threadIdx.x & 63) == 0) wsum[threadIdx.x >> 6] = s;
  __syncthreads();
  if (threadIdx.x == 0) partial[blockIdx.x] = wsum[0] + wsum[1] + wsum[2] + wsum[3];
}

__global__ void csr_scan_partials(const int* __restrict__ partial,
                                  int* __restrict__ pscan, int NP)
{
  if (blockIdx.x == 0 && threadIdx.x == 0) {
    int s = 0;
    for (int i = 0; i < NP; ++i) { pscan[i] = s; s += partial[i]; }
  }
}

__global__ __launch_bounds__(256) void csr_scan_chunk(
    const int* __restrict__ deg, const int* __restrict__ pscan,
    int* __restrict__ row_start, int* __restrict__ cursor, int N)
{
  __shared__ int ls[256];
  int base = blockIdx.x * 1024 + threadIdx.x * 4;
  int v0 = 0, v1 = 0, v2 = 0, v3 = 0;
  if (base + 0 < N) v0 = deg[base + 0];
  if (base + 1 < N) v1 = deg[base + 1];
  if (base + 2 < N) v2 = deg[base + 2];
  if (base + 3 < N) v3 = deg[base + 3];
  int s = v0 + v1 + v2 + v3;
  ls[threadIdx.x] = s;
  __syncthreads();
  for (int off = 1; off < 256; off <<= 1) {
    int t = (threadIdx.x >= off) ? ls[threadIdx.x - off] : 0;
    __syncthreads();
    ls[threadIdx.x] += t;
    __syncthreads();
  }
  int excl = pscan[blockIdx.x] + ls[threadIdx.x] - s;
  int p0 = excl, p1 = excl + v0, p2 = excl + v0 + v1, p3 = excl + v0 + v1 + v2;
  if (base + 0 < N) { row_start[base + 0] = p0; cursor[base + 0] = p0; }
  if (base + 1 < N) { row_start[base + 1] = p1; cursor[base + 1] = p1; }
  if (base + 2 < N) { row_start[base + 2] = p2; cursor[base + 2] = p2; }
  if (base + 3 < N) { row_start[base + 3] = p3; cursor[base + 3] = p3; }
}

// scatter edge's src-id and clamped weight into CSR slot order (no eidx indirection later)
__global__ __launch_bounds__(256) void csr_scatter(
    const int* __restrict__ dst, const int* __restrict__ src,
    const float* __restrict__ ew, int* __restrict__ cursor,
    int* __restrict__ sidx, float* __restrict__ ewc, int E)
{
  int e = blockIdx.x * 256 + threadIdx.x;
  if (e < E) {
    int p = atomicAdd(&cursor[dst[e]], 1);
    sidx[p] = src[e];
    ewc[p] = fmaxf(ew[e], 0.f);
  }
}

// ---------------- fused per-dst attention ----------------
__device__ __forceinline__ void proc_edge(
    float2 qv, float2 kv, float2 vv, float w, float inv_den, float pr,
    float& s, float2& acc)
{
  float t = qv.x * kv.x + qv.y * kv.y;
  t += __shfl_xor(t, 1, 64);
  t += __shfl_xor(t, 2, 64);
  t += __shfl_xor(t, 4, 64);             // 16-dim head dot, broadcast in 8-lane group
  // logits bounded (|dot|<~2, log term in [-20.7,0], pr=0.25) -> exp safe w/o max pass
  float x = __expf((t + __logf(w * inv_den + EPSF)) * pr);
  s += x;
  acc.x = fmaf(x, vv.x, acc.x);
  acc.y = fmaf(x, vv.y, acc.y);
}

// one wave per dst node; lane owns 2 dims; kvs row = [k(128) | v(128)] stride 256
__global__ __launch_bounds__(256) void hgt_dst(
    const float* __restrict__ kvs, const float* __restrict__ q,
    const int* __restrict__ row_start, const int* __restrict__ deg,
    const int* __restrict__ sidx, const float* __restrict__ ewc,
    const float* __restrict__ pri8,
    float* __restrict__ agg, int N)
{
  int n = (blockIdx.x * 256 + threadIdx.x) >> 6;
  int lane = threadIdx.x & 63;
  if (n >= N) return;
  int c0 = lane * 2;
  float* out = agg + (size_t)n * 128;
  int d = deg[n];
  if (d == 0) { *(float2*)(out + c0) = make_float2(0.f, 0.f); return; }
  int base = row_start[n];

  float ds = 0.f;
  for (int j = lane; j < d; j += 64) ds += ewc[base + j];
#pragma unroll
  for (int m = 1; m < 64; m <<= 1) ds += __shfl_xor(ds, m, 64);
  float inv_den = 1.f / fmaxf(ds, EPSF);

  int h = lane >> 3;
  float pr = pri8[h] * 0.25f;            // pri / sqrt(DK)
  float2 qv = *(const float2*)(q + (size_t)n * 128 + c0);

  float s = 0.f;
  float2 acc = make_float2(0.f, 0.f);
  int j = 0;
  for (; j + 4 <= d; j += 4) {           // batch 4 edges: 8 gathers in flight
    int b = base + j;
    int si0 = sidx[b], si1 = sidx[b + 1], si2 = sidx[b + 2], si3 = sidx[b + 3];
    float w0 = ewc[b], w1 = ewc[b + 1], w2 = ewc[b + 2], w3 = ewc[b + 3];
    const float* p0 = kvs + (size_t)si0 * 256 + c0;
    const float* p1 = kvs + (size_t)si1 * 256 + c0;
    const float* p2 = kvs + (size_t)si2 * 256 + c0;
    const float* p3 = kvs + (size_t)si3 * 256 + c0;
    float2 k0 = *(const float2*)p0, v0 = *(const float2*)(p0 + 128);
    float2 k1 = *(const float2*)p1, v1 = *(const float2*)(p1 + 128);
    float2 k2 = *(const float2*)p2, v2 = *(const float2*)(p2 + 128);
    float2 k3 = *(const float2*)p3, v3 = *(const float2*)(p3 + 128);
    proc_edge(qv, k0, v0, w0, inv_den, pr, s, acc);
    proc_edge(qv, k1, v1, w1, inv_den, pr, s, acc);
    proc_edge(qv, k2, v2, w2, inv_den, pr, s, acc);
    proc_edge(qv, k3, v3, w3, inv_den, pr, s, acc);
  }
  for (; j < d; ++j) {
    int b = base + j;
    const float* p = kvs + (size_t)sidx[b] * 256 + c0;
    proc_edge(qv, *(const float2*)p, *(const float2*)(p + 128), ewc[b],
              inv_den, pr, s, acc);
  }
  float is = 1.f / s;
  *(float2*)(out + c0) = make_float2(acc.x * is, acc.y * is);
}

// ---------------- skip-mix + LayerNorm epilogue, one wave per row ----------------
__global__ __launch_bounds__(256) void ln_final(
    const float* __restrict__ tra, const float* __restrict__ trb,
    const float* __restrict__ xa, const float* __restrict__ xb,
    const float* __restrict__ g, const float* __restrict__ bta,
    const float* __restrict__ skip,
    float* __restrict__ out, int NA, int NB)
{
  int wid = (blockIdx.x * 256 + threadIdx.x) >> 6;
  int lane = threadIdx.x & 63;
  if (wid >= NA + NB) return;
  int t; const float *tr, *bs;
  if (wid < NA) { t = 0; tr = tra + (size_t)wid * 128; bs = xa + (size_t)wid * 128; }
  else { t = 1; int r = wid - NA; tr = trb + (size_t)r * 128; bs = xb + (size_t)r * 128; }
  float* o = out + (size_t)wid * 128;
  float alpha = 1.f / (1.f + __expf(-skip[t]));
  float2 tv = *(const float2*)(tr + lane * 2);
  float2 xv = *(const float2*)(bs + lane * 2);
  float o0 = tv.x * alpha + xv.x * (1.f - alpha);
  float o1 = tv.y * alpha + xv.y * (1.f - alpha);
  float sm = o0 + o1;
#pragma unroll
  for (int m = 32; m; m >>= 1) sm += __shfl_xor(sm, m, 64);
  float mu = sm * (1.f / 128.f);
  float d0 = o0 - mu, d1 = o1 - mu;
  float vv = d0 * d0 + d1 * d1;
#pragma unroll
  for (int m = 32; m; m >>= 1) vv += __shfl_xor(vv, m, 64);
  float inv = 1.f / sqrtf(vv * (1.f / 128.f) + 1e-5f);
  int c = lane * 2;
  o[c]     = d0 * inv * g[t * 128 + c]     + bta[t * 128 + c];
  o[c + 1] = d1 * inv * g[t * 128 + c + 1] + bta[t * 128 + c + 1];
}

// ---------------- launch ----------------
extern "C" void kernel_launch(void* const* d_in, const int* in_sizes, int n_in,
                              void* d_out, int out_size, void* d_ws, size_t ws_size,
                              hipStream_t stream)
{
  const float* x_a = (const float*)d_in[0];
  const float* x_b = (const float*)d_in[1];
  const float* ew0 = (const float*)d_in[2];
  const float* ew1 = (const float*)d_in[3];
  const int* src0 = (const int*)d_in[4];
  const int* dst0 = (const int*)d_in[5];
  const int* src1 = (const int*)d_in[6];
  const int* dst1 = (const int*)d_in[7];
  const float* Wk = (const float*)d_in[8];
  const float* bk = (const float*)d_in[9];
  const float* Wq = (const float*)d_in[10];
  const float* bq = (const float*)d_in[11];
  const float* Wv = (const float*)d_in[12];
  const float* bv = (const float*)d_in[13];
  const float* Wa = (const float*)d_in[14];
  const float* ba = (const float*)d_in[15];
  const float* ln_g = (const float*)d_in[16];
  const float* ln_b = (const float*)d_in[17];
  const float* rel_pri = (const float*)d_in[18];
  const float* rel_att = (const float*)d_in[19];
  const float* rel_msg = (const float*)d_in[20];
  const float* skip = (const float*)d_in[21];

  int NA = in_sizes[0] / 128, NB = in_sizes[1] / 128;
  int E0 = in_sizes[2], E1 = in_sizes[3];
  int NMAX = NA > NB ? NA : NB;
  int EMAX = E0 > E1 ? E0 : E1;
  int NM = (NMAX + 255) & ~255;
  int EM = (EMAX + 255) & ~255;

  float* w = (float*)d_ws;
  float* kvb  = w;                               // NM*256 : [k|v] rows (reused as trans later)
  float* qd   = kvb + (size_t)NM * 256;          // NM*128
  float* Wkvf = qd + (size_t)NM * 128;           // 2*128*256
  float* bkvf = Wkvf + 2 * 32768;                // 2*256
  int* deg     = (int*)(bkvf + 512);             // NM
  int* row_st  = deg + NM;                       // NM
  int* cursor  = row_st + NM;                    // NM
  int* sidx    = cursor + NM;                    // EM
  int* partial = sidx + EM;                      // 1024
  int* pscan   = partial + 1024;                 // 1024
  float* ewc   = (float*)(pscan + 1024);         // EM

  float* outf = (float*)d_out;
  float* agg_a = outf;                           // d_out doubles as agg buffer
  float* agg_b = outf + (size_t)NA * 128;
  float* trans_a = kvb;                          // reuse kv space after attention
  float* trans_b = kvb + (size_t)NM * 128;

  dim3 b256(256);
  auto rb = [](int M) { return (unsigned)((M + 63) / 64); };
  auto csr_build = [&](const int* dstp, const int* srcp, const float* ewp, int E, int N) {
    int NP = (N + 1023) / 1024;
    fzero<<<256, b256, 0, stream>>>((float*)deg, N);
    csr_count<<<(E + 255) / 256, b256, 0, stream>>>(dstp, deg, E);
    csr_partial<<<NP, b256, 0, stream>>>(deg, N, partial);
    csr_scan_partials<<<1, 64, 0, stream>>>(partial, pscan, NP);
    csr_scan_chunk<<<NP, b256, 0, stream>>>(deg, pscan, row_st, cursor, N);
    csr_scatter<<<(E + 255) / 256, b256, 0, stream>>>(dstp, srcp, ewp, cursor, sidx, ewc, E);
  };

  fuse_w<<<dim3(129, 2), b256, 0, stream>>>(Wk, bk, Wv, bv, rel_att, rel_msg, Wkvf, bkvf);

  // ---- relation 0: a -> b ----
  gemm_tile<<<dim3(rb(NA), 2), b256, 0, stream>>>(x_a, NA, Wkvf, 256, bkvf, kvb, 256);
  gemm_tile<<<dim3(rb(NB), 1), b256, 0, stream>>>(x_b, NB, Wq + 16384, 128, bq + 128, qd, 128);
  csr_build(dst0, src0, ew0, E0, NB);
  hgt_dst<<<(NB + 3) / 4, b256, 0, stream>>>(kvb, qd, row_st, deg, sidx, ewc,
                                             rel_pri, agg_b, NB);

  // ---- relation 1: b -> a ----
  gemm_tile<<<dim3(rb(NB), 2), b256, 0, stream>>>(x_b, NB, Wkvf + 32768, 256, bkvf + 256, kvb, 256);
  gemm_tile<<<dim3(rb(NA), 1), b256, 0, stream>>>(x_a, NA, Wq, 128, bq, qd, 128);
  csr_build(dst1, src1, ew1, E1, NA);
  hgt_dst<<<(NA + 3) / 4, b256, 0, stream>>>(kvb, qd, row_st, deg, sidx, ewc,
                                             rel_pri + 8, agg_a, NA);

  // ---- output projection (trans = agg @ Wa + ba), reuse kv space ----
  gemm_tile<<<dim3(rb(NA), 1), b256, 0, stream>>>(agg_a, NA, Wa, 128, ba, trans_a, 128);
  gemm_tile<<<dim3(rb(NB), 1), b256, 0, stream>>>(agg_b, NB, Wa + 16384, 128, ba + 128, trans_b, 128);

  int rows = NA + NB;
  ln_final<<<(rows + 3) / 4, b256, 0, stream>>>(trans_a, trans_b, x_a, x_b,
                                                ln_g, ln_b, skip, outf, NA, NB);
}

// Round 7
// 693.191 us; speedup vs baseline: 9.7670x; 1.3922x over previous
//
#include <hip/hip_runtime.h>
#include <cstdint>
#include <cstddef>

#define EPSF 1e-9f

typedef __bf16 bf16x8 __attribute__((ext_vector_type(8)));
typedef float fvec4 __attribute__((ext_vector_type(4)));

__device__ __forceinline__ float blo(unsigned int u) { return __uint_as_float(u << 16); }
__device__ __forceinline__ float bhi(unsigned int u) { return __uint_as_float(u & 0xffff0000u); }
__device__ __forceinline__ unsigned short f2bf(float f) {
  unsigned int u = __float_as_uint(f);
  u += 0x7fffu + ((u >> 16) & 1u);
  return (unsigned short)(u >> 16);
}
__device__ __forceinline__ unsigned int pack2bf(float a, float b) {
  return (unsigned int)f2bf(a) | ((unsigned int)f2bf(b) << 16);
}

// ---------------- zero ----------------
__global__ __launch_bounds__(256) void fzero(float* __restrict__ p, long n) {
  long i = (long)blockIdx.x * blockDim.x + threadIdx.x;
  long stride = (long)gridDim.x * blockDim.x;
  long n4 = n >> 2;
  float4* p4 = (float4*)p;
  for (long j = i; j < n4; j += stride) p4[j] = make_float4(0.f, 0.f, 0.f, 0.f);
  for (long j = (n4 << 2) + i; j < n; j += stride) p[j] = 0.f;
}

// ---------------- fold rel_att/rel_msg into W -> bf16, TRANSPOSED [t][col(256)][k(128)] ----------------
__global__ __launch_bounds__(256) void fuse_w(
    const float* __restrict__ Wk, const float* __restrict__ bk,
    const float* __restrict__ Wv, const float* __restrict__ bv,
    const float* __restrict__ rel_att, const float* __restrict__ rel_msg,
    __bf16* __restrict__ WkvT, float* __restrict__ bkvf)
{
  int i = blockIdx.x;   // 0..128 (128 == bias row)
  int t = blockIdx.y;
  int c = threadIdx.x;  // 0..255: [0,128)=k cols, [128,256)=v cols
  int m = c >> 7, cc = c & 127;
  int h = cc >> 4, e = cc & 15;
  const float* R = (m ? rel_msg : rel_att) + t * 2048 + h * 256;
  const float* srcW = (m ? Wv : Wk) + t * 16384;
  const float* srcB = (m ? bv : bk) + t * 128;
  const float* row = (i < 128) ? (srcW + i * 128) : srcB;
  float acc = 0.f;
#pragma unroll
  for (int d = 0; d < 16; ++d) acc = fmaf(row[h * 16 + d], R[d * 16 + e], acc);
  if (i < 128) WkvT[(size_t)t * 32768 + (size_t)c * 128 + i] = (__bf16)acc;
  else         bkvf[t * 256 + c] = acc;
}

// ---------------- Wq, Wa -> bf16 transposed [t][col][k] ----------------
__global__ __launch_bounds__(128) void cvt_wT(
    const float* __restrict__ Wq, const float* __restrict__ Wa,
    __bf16* __restrict__ WqT, __bf16* __restrict__ WaT)
{
  int k = blockIdx.x, t = blockIdx.y, c = threadIdx.x;
  const float* src = (blockIdx.z ? Wa : Wq) + t * 16384 + k * 128 + c;
  __bf16* dst = (blockIdx.z ? WaT : WqT) + t * 16384 + c * 128 + k;
  dst[0] = (__bf16)src[0];
}

// ---------------- MFMA GEMM: C[bf16, M x (128*gy)] = A[f32 Mx128] @ WT + bias ----------------
// block 256 = 4 waves (2m x 2n), tile 64r x 128c; no LDS, A packed f32->bf16 in regs,
// B-fragments read from L2-resident transposed bf16 weights.
__global__ __launch_bounds__(256) void gemm_mfma(
    const float* __restrict__ A, int M,
    const __bf16* __restrict__ WT, const float* __restrict__ bias,
    __bf16* __restrict__ C, int ldc)
{
  int tid = threadIdx.x, l = tid & 63, wid = tid >> 6;
  int l15 = l & 15, l4 = l >> 4;
  int rowb = blockIdx.x * 64 + (wid & 1) * 32;
  int colb = blockIdx.y * 128 + (wid >> 1) * 64;

  fvec4 z = {0.f, 0.f, 0.f, 0.f};
  fvec4 acc[2][4];
#pragma unroll
  for (int m = 0; m < 2; ++m)
#pragma unroll
    for (int n = 0; n < 4; ++n) acc[m][n] = z;

#pragma unroll
  for (int ks = 0; ks < 4; ++ks) {
    int kb = ks * 32 + l4 * 8;
    bf16x8 af[2], bfr[4];
#pragma unroll
    for (int m = 0; m < 2; ++m) {
      int r = rowb + m * 16 + l15;
      r = r < M ? r : M - 1;
      const float4* ap = (const float4*)(A + (size_t)r * 128 + kb);
      float4 a0 = ap[0], a1 = ap[1];
      bf16x8 v;
      v[0] = (__bf16)a0.x; v[1] = (__bf16)a0.y; v[2] = (__bf16)a0.z; v[3] = (__bf16)a0.w;
      v[4] = (__bf16)a1.x; v[5] = (__bf16)a1.y; v[6] = (__bf16)a1.z; v[7] = (__bf16)a1.w;
      af[m] = v;
    }
#pragma unroll
    for (int n = 0; n < 4; ++n)
      bfr[n] = *(const bf16x8*)(WT + (size_t)(colb + n * 16 + l15) * 128 + kb);
#pragma unroll
    for (int m = 0; m < 2; ++m)
#pragma unroll
      for (int n = 0; n < 4; ++n)
        acc[m][n] = __builtin_amdgcn_mfma_f32_16x16x32_bf16(af[m], bfr[n], acc[m][n], 0, 0, 0);
  }

#pragma unroll
  for (int m = 0; m < 2; ++m)
#pragma unroll
    for (int n = 0; n < 4; ++n) {
      int col = colb + n * 16 + l15;
      float bcol = bias[col];
#pragma unroll
      for (int reg = 0; reg < 4; ++reg) {
        int r = rowb + m * 16 + l4 * 4 + reg;
        if (r < M) C[(size_t)r * ldc + col] = (__bf16)(acc[m][n][reg] + bcol);
      }
    }
}

// ---------------- CSR build (both relations concatenated: [NB dsts | NA dsts]) ----------------
__global__ __launch_bounds__(256) void csr_count2(
    const int* __restrict__ dst0, int E0, const int* __restrict__ dst1, int E1,
    int* __restrict__ deg, int NB)
{
  int e = blockIdx.x * 256 + threadIdx.x;
  if (e < E0) atomicAdd(&deg[dst0[e]], 1);
  else if (e < E0 + E1) atomicAdd(&deg[NB + dst1[e - E0]], 1);
}

__global__ __launch_bounds__(256) void csr_partial(
    const int* __restrict__ deg, int N, int* __restrict__ partial)
{
  int base = blockIdx.x * 1024 + threadIdx.x * 4;
  int s = 0;
#pragma unroll
  for (int i = 0; i < 4; ++i) if (base + i < N) s += deg[base + i];
#pragma unroll
  for (int m = 1; m < 64; m <<= 1) s += __shfl_xor(s, m, 64);
  __shared__ int wsum[4];
  if ((threadIdx.x & 63) == 0) wsum[threadIdx.x >> 6] = s;
  __syncthreads();
  if (threadIdx.x == 0) partial[blockIdx.x] = wsum[0] + wsum[1] + wsum[2] + wsum[3];
}

__global__ void csr_scan_partials(const int* __restrict__ partial,
                                  int* __restrict__ pscan, int NP)
{
  if (blockIdx.x == 0 && threadIdx.x == 0) {
    int s = 0;
    for (int i = 0; i < NP; ++i) { pscan[i] = s; s += partial[i]; }
  }
}

__global__ __launch_bounds__(256) void csr_scan_chunk(
    const int* __restrict__ deg, const int* __restrict__ pscan,
    int* __restrict__ row_start, int* __restrict__ cursor, int N)
{
  __shared__ int ls[256];
  int base = blockIdx.x * 1024 + threadIdx.x * 4;
  int v0 = 0, v1 = 0, v2 = 0, v3 = 0;
  if (base + 0 < N) v0 = deg[base + 0];
  if (base + 1 < N) v1 = deg[base + 1];
  if (base + 2 < N) v2 = deg[base + 2];
  if (base + 3 < N) v3 = deg[base + 3];
  int s = v0 + v1 + v2 + v3;
  ls[threadIdx.x] = s;
  __syncthreads();
  for (int off = 1; off < 256; off <<= 1) {
    int t = (threadIdx.x >= off) ? ls[threadIdx.x - off] : 0;
    __syncthreads();
    ls[threadIdx.x] += t;
    __syncthreads();
  }
  int excl = pscan[blockIdx.x] + ls[threadIdx.x] - s;
  int p0 = excl, p1 = excl + v0, p2 = excl + v0 + v1, p3 = excl + v0 + v1 + v2;
  if (base + 0 < N) { row_start[base + 0] = p0; cursor[base + 0] = p0; }
  if (base + 1 < N) { row_start[base + 1] = p1; cursor[base + 1] = p1; }
  if (base + 2 < N) { row_start[base + 2] = p2; cursor[base + 2] = p2; }
  if (base + 3 < N) { row_start[base + 3] = p3; cursor[base + 3] = p3; }
}

__global__ __launch_bounds__(256) void csr_scatter2(
    const int* __restrict__ dst0, const int* __restrict__ src0, const float* __restrict__ ew0, int E0,
    const int* __restrict__ dst1, const int* __restrict__ src1, const float* __restrict__ ew1, int E1,
    int* __restrict__ cursor, int* __restrict__ sidx, float* __restrict__ ewc, int NB)
{
  int e = blockIdx.x * 256 + threadIdx.x;
  if (e < E0) {
    int p = atomicAdd(&cursor[dst0[e]], 1);
    sidx[p] = src0[e];
    ewc[p] = fmaxf(ew0[e], 0.f);
  } else if (e < E0 + E1) {
    int e1 = e - E0;
    int p = atomicAdd(&cursor[NB + dst1[e1]], 1);
    sidx[p] = src1[e1];
    ewc[p] = fmaxf(ew1[e1], 0.f);
  }
}

// ---------------- fused per-dst attention (bf16 activations) ----------------
__device__ __forceinline__ void proc_edge(
    float qlo, float qhi, unsigned int ku, unsigned int vu, float w,
    float inv_den, float pr, float& s, float2& acc)
{
  float t = qlo * blo(ku) + qhi * bhi(ku);
  t += __shfl_xor(t, 1, 64);
  t += __shfl_xor(t, 2, 64);
  t += __shfl_xor(t, 4, 64);             // 16-dim head dot broadcast in 8-lane group
  float x = __expf((t + __logf(w * inv_den + EPSF)) * pr);
  s += x;
  acc.x = fmaf(x, blo(vu), acc.x);
  acc.y = fmaf(x, bhi(vu), acc.y);
}

// one 64-lane wave per dst node; lane owns 2 dims; kvs row = [k(128)|v(128)] bf16, stride 256
__global__ __launch_bounds__(256) void hgt_dst(
    const __bf16* __restrict__ kvsb, const __bf16* __restrict__ qb,
    const int* __restrict__ row_start, const int* __restrict__ deg,
    const int* __restrict__ sidx, const float* __restrict__ ewc,
    const float* __restrict__ pri8,
    __bf16* __restrict__ agg, int N)
{
  const unsigned short* kvs = (const unsigned short*)kvsb;
  int n = (blockIdx.x * 256 + threadIdx.x) >> 6;
  int lane = threadIdx.x & 63;
  if (n >= N) return;
  int c0 = lane * 2;
  unsigned int* out = (unsigned int*)(agg + (size_t)n * 128 + c0);
  int d = deg[n];
  if (d == 0) { out[0] = 0u; return; }
  int base = row_start[n];

  float ds = 0.f;
  for (int j = lane; j < d; j += 64) ds += ewc[base + j];
#pragma unroll
  for (int m = 1; m < 64; m <<= 1) ds += __shfl_xor(ds, m, 64);
  float inv_den = 1.f / fmaxf(ds, EPSF);

  int h = lane >> 3;
  float pr = pri8[h] * 0.25f;            // pri / sqrt(DK)
  unsigned int qu = *(const unsigned int*)((const unsigned short*)qb + (size_t)n * 128 + c0);
  float qlo = blo(qu), qhi = bhi(qu);

  float s = 0.f;
  float2 acc = make_float2(0.f, 0.f);
  int j = 0;
  for (; j + 4 <= d; j += 4) {           // batch 4 edges: 8 gathers in flight
    int b = base + j;
    int si0 = sidx[b], si1 = sidx[b + 1], si2 = sidx[b + 2], si3 = sidx[b + 3];
    float w0 = ewc[b], w1 = ewc[b + 1], w2 = ewc[b + 2], w3 = ewc[b + 3];
    const unsigned short* p0 = kvs + (size_t)si0 * 256 + c0;
    const unsigned short* p1 = kvs + (size_t)si1 * 256 + c0;
    const unsigned short* p2 = kvs + (size_t)si2 * 256 + c0;
    const unsigned short* p3 = kvs + (size_t)si3 * 256 + c0;
    unsigned int k0 = *(const unsigned int*)p0, v0 = *(const unsigned int*)(p0 + 128);
    unsigned int k1 = *(const unsigned int*)p1, v1 = *(const unsigned int*)(p1 + 128);
    unsigned int k2 = *(const unsigned int*)p2, v2 = *(const unsigned int*)(p2 + 128);
    unsigned int k3 = *(const unsigned int*)p3, v3 = *(const unsigned int*)(p3 + 128);
    proc_edge(qlo, qhi, k0, v0, w0, inv_den, pr, s, acc);
    proc_edge(qlo, qhi, k1, v1, w1, inv_den, pr, s, acc);
    proc_edge(qlo, qhi, k2, v2, w2, inv_den, pr, s, acc);
    proc_edge(qlo, qhi, k3, v3, w3, inv_den, pr, s, acc);
  }
  for (; j < d; ++j) {
    int b = base + j;
    const unsigned short* p = kvs + (size_t)sidx[b] * 256 + c0;
    proc_edge(qlo, qhi, *(const unsigned int*)p, *(const unsigned int*)(p + 128),
              ewc[b], inv_den, pr, s, acc);
  }
  float is = 1.f / s;
  out[0] = pack2bf(acc.x * is, acc.y * is);
}

// ---------------- fused Wa-projection + skip-mix + LayerNorm ----------------
// block 256 = 4 waves x 16 rows; wave owns 16 full rows (128 cols) -> LN via 16-lane shuffles
__global__ __launch_bounds__(256) void wa_ln(
    const __bf16* __restrict__ Ag, const __bf16* __restrict__ WT,
    const float* __restrict__ bias, const float* __restrict__ xbase,
    const float* __restrict__ g, const float* __restrict__ bb,
    const float* __restrict__ skip, float* __restrict__ out, int M)
{
  int tid = threadIdx.x, l = tid & 63, wid = tid >> 6;
  int l15 = l & 15, l4 = l >> 4;
  int rowb = blockIdx.x * 64 + wid * 16;

  fvec4 z = {0.f, 0.f, 0.f, 0.f};
  fvec4 acc[8];
#pragma unroll
  for (int n = 0; n < 8; ++n) acc[n] = z;

#pragma unroll
  for (int ks = 0; ks < 4; ++ks) {
    int kb = ks * 32 + l4 * 8;
    int r = rowb + l15;
    r = r < M ? r : M - 1;
    bf16x8 af = *(const bf16x8*)(Ag + (size_t)r * 128 + kb);
#pragma unroll
    for (int n = 0; n < 8; ++n) {
      bf16x8 bfr = *(const bf16x8*)(WT + (size_t)(n * 16 + l15) * 128 + kb);
      acc[n] = __builtin_amdgcn_mfma_f32_16x16x32_bf16(af, bfr, acc[n], 0, 0, 0);
    }
  }

  float alpha = 1.f / (1.f + __expf(-skip[0]));
  float onema = 1.f - alpha;
  float o[8][4];
  float psum[4] = {0.f, 0.f, 0.f, 0.f};
  float psq[4] = {0.f, 0.f, 0.f, 0.f};
#pragma unroll
  for (int n = 0; n < 8; ++n) {
    int col = n * 16 + l15;
    float bcol = bias[col];
#pragma unroll
    for (int reg = 0; reg < 4; ++reg) {
      int r = rowb + l4 * 4 + reg;
      float xv = (r < M) ? xbase[(size_t)r * 128 + col] : 0.f;
      float val = (acc[n][reg] + bcol) * alpha + xv * onema;
      o[n][reg] = val;
      psum[reg] += val;
      psq[reg] = fmaf(val, val, psq[reg]);
    }
  }
#pragma unroll
  for (int reg = 0; reg < 4; ++reg) {
#pragma unroll
    for (int m = 1; m < 16; m <<= 1) {
      psum[reg] += __shfl_xor(psum[reg], m, 64);
      psq[reg] += __shfl_xor(psq[reg], m, 64);
    }
  }
  float mu[4], is[4];
#pragma unroll
  for (int reg = 0; reg < 4; ++reg) {
    mu[reg] = psum[reg] * (1.f / 128.f);
    float var = psq[reg] * (1.f / 128.f) - mu[reg] * mu[reg];
    is[reg] = 1.f / sqrtf(var + 1e-5f);
  }
#pragma unroll
  for (int n = 0; n < 8; ++n) {
    int col = n * 16 + l15;
    float gc = g[col], bc = bb[col];
#pragma unroll
    for (int reg = 0; reg < 4; ++reg) {
      int r = rowb + l4 * 4 + reg;
      if (r < M) out[(size_t)r * 128 + col] = (o[n][reg] - mu[reg]) * is[reg] * gc + bc;
    }
  }
}

// ---------------- launch ----------------
extern "C" void kernel_launch(void* const* d_in, const int* in_sizes, int n_in,
                              void* d_out, int out_size, void* d_ws, size_t ws_size,
                              hipStream_t stream)
{
  const float* x_a = (const float*)d_in[0];
  const float* x_b = (const float*)d_in[1];
  const float* ew0 = (const float*)d_in[2];
  const float* ew1 = (const float*)d_in[3];
  const int* src0 = (const int*)d_in[4];
  const int* dst0 = (const int*)d_in[5];
  const int* src1 = (const int*)d_in[6];
  const int* dst1 = (const int*)d_in[7];
  const float* Wk = (const float*)d_in[8];
  const float* bk = (const float*)d_in[9];
  const float* Wq = (const float*)d_in[10];
  const float* bq = (const float*)d_in[11];
  const float* Wv = (const float*)d_in[12];
  const float* bv = (const float*)d_in[13];
  const float* Wa = (const float*)d_in[14];
  const float* ba = (const float*)d_in[15];
  const float* ln_g = (const float*)d_in[16];
  const float* ln_b = (const float*)d_in[17];
  const float* rel_pri = (const float*)d_in[18];
  const float* rel_att = (const float*)d_in[19];
  const float* rel_msg = (const float*)d_in[20];
  const float* skip = (const float*)d_in[21];

  int NA = in_sizes[0] / 128, NB = in_sizes[1] / 128;
  int E0 = in_sizes[2], E1 = in_sizes[3];
  int NMAX = NA > NB ? NA : NB;
  int NM = (NMAX + 255) & ~255;
  int N2 = NA + NB;
  int N2M = (N2 + 255) & ~255;
  int E2 = E0 + E1;
  int E2M = (E2 + 255) & ~255;

  char* wsbase = (char*)d_ws;
  size_t off = 0;
  auto alloc = [&](size_t bytes) { char* p = wsbase + off; off += (bytes + 255) & ~(size_t)255; return p; };
  __bf16* kvb   = (__bf16*)alloc((size_t)NM * 256 * 2);
  __bf16* qd    = (__bf16*)alloc((size_t)NM * 128 * 2);
  __bf16* agg_a = (__bf16*)alloc((size_t)NM * 128 * 2);
  __bf16* agg_b = (__bf16*)alloc((size_t)NM * 128 * 2);
  __bf16* WkvT  = (__bf16*)alloc(2 * 256 * 128 * 2);
  __bf16* WqT   = (__bf16*)alloc(2 * 128 * 128 * 2);
  __bf16* WaT   = (__bf16*)alloc(2 * 128 * 128 * 2);
  float* bkvf   = (float*)alloc(2 * 256 * 4);
  int* deg      = (int*)alloc((size_t)N2M * 4);
  int* row_st   = (int*)alloc((size_t)N2M * 4);
  int* cur      = (int*)alloc((size_t)N2M * 4);
  int* partial  = (int*)alloc(1024 * 4);
  int* pscan    = (int*)alloc(1024 * 4);
  int* sidx     = (int*)alloc((size_t)E2M * 4);
  float* ewc    = (float*)alloc((size_t)E2M * 4);

  float* outf = (float*)d_out;
  dim3 b256(256);
  auto cdiv = [](int a, int b) { return (unsigned)((a + b - 1) / b); };

  // weights prep
  fuse_w<<<dim3(129, 2), b256, 0, stream>>>(Wk, bk, Wv, bv, rel_att, rel_msg, WkvT, bkvf);
  cvt_wT<<<dim3(128, 2, 2), 128, 0, stream>>>(Wq, Wa, WqT, WaT);

  // CSR for both relations, concatenated [NB | NA]
  int NP = (N2 + 1023) / 1024;
  fzero<<<64, b256, 0, stream>>>((float*)deg, N2);
  csr_count2<<<cdiv(E2, 256), b256, 0, stream>>>(dst0, E0, dst1, E1, deg, NB);
  csr_partial<<<NP, b256, 0, stream>>>(deg, N2, partial);
  csr_scan_partials<<<1, 64, 0, stream>>>(partial, pscan, NP);
  csr_scan_chunk<<<NP, b256, 0, stream>>>(deg, pscan, row_st, cur, N2);
  csr_scatter2<<<cdiv(E2, 256), b256, 0, stream>>>(dst0, src0, ew0, E0,
                                                   dst1, src1, ew1, E1,
                                                   cur, sidx, ewc, NB);

  // ---- relation 0: a -> b ----
  gemm_mfma<<<dim3(cdiv(NA, 64), 2), b256, 0, stream>>>(x_a, NA, WkvT, bkvf, kvb, 256);
  gemm_mfma<<<dim3(cdiv(NB, 64), 1), b256, 0, stream>>>(x_b, NB, WqT + 16384, bq + 128, qd, 128);
  hgt_dst<<<cdiv(NB, 4), b256, 0, stream>>>(kvb, qd, row_st, deg, sidx, ewc,
                                            rel_pri, agg_b, NB);

  // ---- relation 1: b -> a ----
  gemm_mfma<<<dim3(cdiv(NB, 64), 2), b256, 0, stream>>>(x_b, NB, WkvT + 32768, bkvf + 256, kvb, 256);
  gemm_mfma<<<dim3(cdiv(NA, 64), 1), b256, 0, stream>>>(x_a, NA, WqT, bq, qd, 128);
  hgt_dst<<<cdiv(NA, 4), b256, 0, stream>>>(kvb, qd, row_st + NB, deg + NB, sidx, ewc,
                                            rel_pri + 8, agg_a, NA);

  // ---- fused Wa projection + skip + LayerNorm ----
  wa_ln<<<cdiv(NA, 64), b256, 0, stream>>>(agg_a, WaT, ba, x_a, ln_g, ln_b, skip, outf, NA);
  wa_ln<<<cdiv(NB, 64), b256, 0, stream>>>(agg_b, WaT + 16384, ba + 128, x_b,
                                           ln_g + 128, ln_b + 128, skip + 1,
                                           outf + (size_t)NA * 128, NB);
}

// Round 8
// 627.300 us; speedup vs baseline: 10.7929x; 1.1050x over previous
//
#include <hip/hip_runtime.h>
#include <cstdint>
#include <cstddef>

#define EPSF 1e-9f

typedef __bf16 bf16x8 __attribute__((ext_vector_type(8)));
typedef float fvec4 __attribute__((ext_vector_type(4)));

__device__ __forceinline__ float blo(unsigned int u) { return __uint_as_float(u << 16); }
__device__ __forceinline__ float bhi(unsigned int u) { return __uint_as_float(u & 0xffff0000u); }
__device__ __forceinline__ unsigned short f2bf(float f) {
  unsigned int u = __float_as_uint(f);
  u += 0x7fffu + ((u >> 16) & 1u);
  return (unsigned short)(u >> 16);
}
__device__ __forceinline__ unsigned int pack2bf(float a, float b) {
  return (unsigned int)f2bf(a) | ((unsigned int)f2bf(b) << 16);
}

// ---------------- zero ----------------
__global__ __launch_bounds__(256) void fzero(float* __restrict__ p, long n) {
  long i = (long)blockIdx.x * blockDim.x + threadIdx.x;
  long stride = (long)gridDim.x * blockDim.x;
  long n4 = n >> 2;
  float4* p4 = (float4*)p;
  for (long j = i; j < n4; j += stride) p4[j] = make_float4(0.f, 0.f, 0.f, 0.f);
  for (long j = (n4 << 2) + i; j < n; j += stride) p[j] = 0.f;
}

// ---- fold rel_att/rel_msg into Wk/Wv -> rows 0..255 of WkvqT[t] (layout [384 cols][128 k], bf16) ----
__global__ __launch_bounds__(256) void fuse_w(
    const float* __restrict__ Wk, const float* __restrict__ bk,
    const float* __restrict__ Wv, const float* __restrict__ bv,
    const float* __restrict__ rel_att, const float* __restrict__ rel_msg,
    __bf16* __restrict__ WkvqT, float* __restrict__ bkvq)
{
  int i = blockIdx.x;   // 0..128 (128 == bias row)
  int t = blockIdx.y;
  int c = threadIdx.x;  // 0..255: [0,128)=k cols, [128,256)=v cols
  int m = c >> 7, cc = c & 127;
  int h = cc >> 4, e = cc & 15;
  const float* R = (m ? rel_msg : rel_att) + t * 2048 + h * 256;
  const float* srcW = (m ? Wv : Wk) + t * 16384;
  const float* srcB = (m ? bv : bk) + t * 128;
  const float* row = (i < 128) ? (srcW + i * 128) : srcB;
  float acc = 0.f;
#pragma unroll
  for (int d = 0; d < 16; ++d) acc = fmaf(row[h * 16 + d], R[d * 16 + e], acc);
  if (i < 128) WkvqT[(size_t)t * 49152 + (size_t)c * 128 + i] = (__bf16)acc;
  else         bkvq[t * 384 + c] = acc;
}

// ---- Wq -> rows 256..383 of WkvqT[t] (+q bias); Wa -> WaT [t][col][k] ----
__global__ __launch_bounds__(128) void cvt_wT(
    const float* __restrict__ Wq, const float* __restrict__ bq,
    const float* __restrict__ Wa,
    __bf16* __restrict__ WkvqT, __bf16* __restrict__ WaT,
    float* __restrict__ bkvq)
{
  int k = blockIdx.x, t = blockIdx.y, c = threadIdx.x;
  if (blockIdx.z == 0) {
    WkvqT[(size_t)t * 49152 + (size_t)(256 + c) * 128 + k] = (__bf16)Wq[t * 16384 + k * 128 + c];
    if (k == 0) bkvq[t * 384 + 256 + c] = bq[t * 128 + c];
  } else {
    WaT[(size_t)t * 16384 + (size_t)c * 128 + k] = (__bf16)Wa[t * 16384 + k * 128 + c];
  }
}

// ---------------- fused KVQ MFMA GEMM ----------------
// One dispatch per node type: [KV(256 cols) | Q(128 cols)] = A[Mx128 f32] @ WT[384x128 bf16].
// Block = 64 rows, 4 waves (2m x 2n). A staged to LDS as bf16 with XOR swizzle
// (conversion off the MFMA path, conflict-free ds_read_b128), A-frags hoisted to
// registers once and reused across the 3 column tiles. B from L2-resident WT.
__global__ __launch_bounds__(256) void gemm_kvq(
    const float* __restrict__ A, int M,
    const __bf16* __restrict__ WT, const float* __restrict__ bias,
    __bf16* __restrict__ KV, __bf16* __restrict__ Q)
{
  __shared__ __bf16 As[64 * 128];  // 16 KB, swizzled: byte ^= (row&7)<<4
  const int tid = threadIdx.x;
  const int rowb = blockIdx.x * 64;

#pragma unroll
  for (int i = 0; i < 4; ++i) {     // stage+convert: thread -> 8 f32 -> bf16x8 -> 16B ds_write
    int f = tid + i * 256;          // chunk id 0..1023
    int r = f >> 4;                 // row 0..63
    int ch = f & 15;                // 16-B chunk (8 bf16) within row
    int gr = rowb + r; gr = gr < M ? gr : M - 1;
    const float4* ap = (const float4*)(A + (size_t)gr * 128 + ch * 8);
    float4 a0 = ap[0], a1 = ap[1];
    bf16x8 v;
    v[0] = (__bf16)a0.x; v[1] = (__bf16)a0.y; v[2] = (__bf16)a0.z; v[3] = (__bf16)a0.w;
    v[4] = (__bf16)a1.x; v[5] = (__bf16)a1.y; v[6] = (__bf16)a1.z; v[7] = (__bf16)a1.w;
    int sw = (ch * 16) ^ ((r & 7) << 4);
    *(bf16x8*)((char*)As + r * 256 + sw) = v;
  }
  __syncthreads();

  const int l = tid & 63, wid = tid >> 6;
  const int l15 = l & 15, l4 = l >> 4;
  const int wm = wid & 1, wn = wid >> 1;

  bf16x8 af[2][4];                  // A-frags: 2 m-blocks x 4 k-steps, reused for all tiles
#pragma unroll
  for (int m = 0; m < 2; ++m)
#pragma unroll
    for (int ks = 0; ks < 4; ++ks) {
      int r = wm * 32 + m * 16 + l15;
      int off = (ks * 64 + l4 * 16) ^ ((r & 7) << 4);
      af[m][ks] = *(const bf16x8*)((const char*)As + r * 256 + off);
    }

#pragma unroll
  for (int t = 0; t < 3; ++t) {     // 3 column tiles: 0,1 -> KV; 2 -> Q
    const int colb = t * 128 + wn * 64;
    fvec4 z = {0.f, 0.f, 0.f, 0.f};
    fvec4 acc[2][4];
#pragma unroll
    for (int m = 0; m < 2; ++m)
#pragma unroll
      for (int n = 0; n < 4; ++n) acc[m][n] = z;

    bf16x8 bfr[4][4];
#pragma unroll
    for (int n = 0; n < 4; ++n)
#pragma unroll
      for (int ks = 0; ks < 4; ++ks)
        bfr[n][ks] = *(const bf16x8*)(WT + (size_t)(colb + n * 16 + l15) * 128 + ks * 32 + l4 * 8);

#pragma unroll
    for (int ks = 0; ks < 4; ++ks)
#pragma unroll
      for (int m = 0; m < 2; ++m)
#pragma unroll
        for (int n = 0; n < 4; ++n)
          acc[m][n] = __builtin_amdgcn_mfma_f32_16x16x32_bf16(af[m][ks], bfr[n][ks], acc[m][n], 0, 0, 0);

    __bf16* Cp = (t < 2) ? KV : Q;
    const int ldc = (t < 2) ? 256 : 128;
    const int cbase = (t < 2) ? colb : wn * 64;
#pragma unroll
    for (int m = 0; m < 2; ++m)
#pragma unroll
      for (int n = 0; n < 4; ++n) {
        int col = cbase + n * 16 + l15;
        float bcol = bias[colb + n * 16 + l15];
#pragma unroll
        for (int reg = 0; reg < 4; ++reg) {
          int r = rowb + wm * 32 + m * 16 + l4 * 4 + reg;
          if (r < M) Cp[(size_t)r * ldc + col] = (__bf16)(acc[m][n][reg] + bcol);
        }
      }
  }
}

// ---------------- CSR build (both relations concatenated: [NB dsts | NA dsts]) ----------------
__global__ __launch_bounds__(256) void csr_count2(
    const int* __restrict__ dst0, int E0, const int* __restrict__ dst1, int E1,
    int* __restrict__ deg, int NB)
{
  int e = blockIdx.x * 256 + threadIdx.x;
  if (e < E0) atomicAdd(&deg[dst0[e]], 1);
  else if (e < E0 + E1) atomicAdd(&deg[NB + dst1[e - E0]], 1);
}

__global__ __launch_bounds__(256) void csr_partial(
    const int* __restrict__ deg, int N, int* __restrict__ partial)
{
  int base = blockIdx.x * 1024 + threadIdx.x * 4;
  int s = 0;
#pragma unroll
  for (int i = 0; i < 4; ++i) if (base + i < N) s += deg[base + i];
#pragma unroll
  for (int m = 1; m < 64; m <<= 1) s += __shfl_xor(s, m, 64);
  __shared__ int wsum[4];
  if ((threadIdx.x & 63) == 0) wsum[threadIdx.x >> 6] = s;
  __syncthreads();
  if (threadIdx.x == 0) partial[blockIdx.x] = wsum[0] + wsum[1] + wsum[2] + wsum[3];
}

__global__ void csr_scan_partials(const int* __restrict__ partial,
                                  int* __restrict__ pscan, int NP)
{
  if (blockIdx.x == 0 && threadIdx.x == 0) {
    int s = 0;
    for (int i = 0; i < NP; ++i) { pscan[i] = s; s += partial[i]; }
  }
}

__global__ __launch_bounds__(256) void csr_scan_chunk(
    const int* __restrict__ deg, const int* __restrict__ pscan,
    int* __restrict__ row_start, int* __restrict__ cursor, int N)
{
  __shared__ int ls[256];
  int base = blockIdx.x * 1024 + threadIdx.x * 4;
  int v0 = 0, v1 = 0, v2 = 0, v3 = 0;
  if (base + 0 < N) v0 = deg[base + 0];
  if (base + 1 < N) v1 = deg[base + 1];
  if (base + 2 < N) v2 = deg[base + 2];
  if (base + 3 < N) v3 = deg[base + 3];
  int s = v0 + v1 + v2 + v3;
  ls[threadIdx.x] = s;
  __syncthreads();
  for (int off = 1; off < 256; off <<= 1) {
    int t = (threadIdx.x >= off) ? ls[threadIdx.x - off] : 0;
    __syncthreads();
    ls[threadIdx.x] += t;
    __syncthreads();
  }
  int excl = pscan[blockIdx.x] + ls[threadIdx.x] - s;
  int p0 = excl, p1 = excl + v0, p2 = excl + v0 + v1, p3 = excl + v0 + v1 + v2;
  if (base + 0 < N) { row_start[base + 0] = p0; cursor[base + 0] = p0; }
  if (base + 1 < N) { row_start[base + 1] = p1; cursor[base + 1] = p1; }
  if (base + 2 < N) { row_start[base + 2] = p2; cursor[base + 2] = p2; }
  if (base + 3 < N) { row_start[base + 3] = p3; cursor[base + 3] = p3; }
}

__global__ __launch_bounds__(256) void csr_scatter2(
    const int* __restrict__ dst0, const int* __restrict__ src0, const float* __restrict__ ew0, int E0,
    const int* __restrict__ dst1, const int* __restrict__ src1, const float* __restrict__ ew1, int E1,
    int* __restrict__ cursor, int* __restrict__ sidx, float* __restrict__ ewc, int NB)
{
  int e = blockIdx.x * 256 + threadIdx.x;
  if (e < E0) {
    int p = atomicAdd(&cursor[dst0[e]], 1);
    sidx[p] = src0[e];
    ewc[p] = fmaxf(ew0[e], 0.f);
  } else if (e < E0 + E1) {
    int e1 = e - E0;
    int p = atomicAdd(&cursor[NB + dst1[e1]], 1);
    sidx[p] = src1[e1];
    ewc[p] = fmaxf(ew1[e1], 0.f);
  }
}

// ---------------- fused per-dst attention (bf16 activations) ----------------
__device__ __forceinline__ void proc_edge(
    float qlo, float qhi, unsigned int ku, unsigned int vu, float w,
    float inv_den, float pr, float& s, float2& acc)
{
  float t = qlo * blo(ku) + qhi * bhi(ku);
  t += __shfl_xor(t, 1, 64);
  t += __shfl_xor(t, 2, 64);
  t += __shfl_xor(t, 4, 64);             // 16-dim head dot broadcast in 8-lane group
  float x = __expf((t + __logf(w * inv_den + EPSF)) * pr);
  s += x;
  acc.x = fmaf(x, blo(vu), acc.x);
  acc.y = fmaf(x, bhi(vu), acc.y);
}

// one 64-lane wave per dst node; lane owns 2 dims; kvs row = [k(128)|v(128)] bf16, stride 256
__global__ __launch_bounds__(256) void hgt_dst(
    const __bf16* __restrict__ kvsb, const __bf16* __restrict__ qb,
    const int* __restrict__ row_start, const int* __restrict__ deg,
    const int* __restrict__ sidx, const float* __restrict__ ewc,
    const float* __restrict__ pri8,
    __bf16* __restrict__ agg, int N)
{
  const unsigned short* kvs = (const unsigned short*)kvsb;
  int n = (blockIdx.x * 256 + threadIdx.x) >> 6;
  int lane = threadIdx.x & 63;
  if (n >= N) return;
  int c0 = lane * 2;
  unsigned int* out = (unsigned int*)(agg + (size_t)n * 128 + c0);
  int d = deg[n];
  if (d == 0) { out[0] = 0u; return; }
  int base = row_start[n];

  float ds = 0.f;
  for (int j = lane; j < d; j += 64) ds += ewc[base + j];
#pragma unroll
  for (int m = 1; m < 64; m <<= 1) ds += __shfl_xor(ds, m, 64);
  float inv_den = 1.f / fmaxf(ds, EPSF);

  int h = lane >> 3;
  float pr = pri8[h] * 0.25f;            // pri / sqrt(DK)
  unsigned int qu = *(const unsigned int*)((const unsigned short*)qb + (size_t)n * 128 + c0);
  float qlo = blo(qu), qhi = bhi(qu);

  float s = 0.f;
  float2 acc = make_float2(0.f, 0.f);
  int j = 0;
  for (; j + 4 <= d; j += 4) {           // batch 4 edges: 8 gathers in flight
    int b = base + j;
    int si0 = sidx[b], si1 = sidx[b + 1], si2 = sidx[b + 2], si3 = sidx[b + 3];
    float w0 = ewc[b], w1 = ewc[b + 1], w2 = ewc[b + 2], w3 = ewc[b + 3];
    const unsigned short* p0 = kvs + (size_t)si0 * 256 + c0;
    const unsigned short* p1 = kvs + (size_t)si1 * 256 + c0;
    const unsigned short* p2 = kvs + (size_t)si2 * 256 + c0;
    const unsigned short* p3 = kvs + (size_t)si3 * 256 + c0;
    unsigned int k0 = *(const unsigned int*)p0, v0 = *(const unsigned int*)(p0 + 128);
    unsigned int k1 = *(const unsigned int*)p1, v1 = *(const unsigned int*)(p1 + 128);
    unsigned int k2 = *(const unsigned int*)p2, v2 = *(const unsigned int*)(p2 + 128);
    unsigned int k3 = *(const unsigned int*)p3, v3 = *(const unsigned int*)(p3 + 128);
    proc_edge(qlo, qhi, k0, v0, w0, inv_den, pr, s, acc);
    proc_edge(qlo, qhi, k1, v1, w1, inv_den, pr, s, acc);
    proc_edge(qlo, qhi, k2, v2, w2, inv_den, pr, s, acc);
    proc_edge(qlo, qhi, k3, v3, w3, inv_den, pr, s, acc);
  }
  for (; j < d; ++j) {
    int b = base + j;
    const unsigned short* p = kvs + (size_t)sidx[b] * 256 + c0;
    proc_edge(qlo, qhi, *(const unsigned int*)p, *(const unsigned int*)(p + 128),
              ewc[b], inv_den, pr, s, acc);
  }
  float is = 1.f / s;
  out[0] = pack2bf(acc.x * is, acc.y * is);
}

// ---------------- fused Wa-projection + skip-mix + LayerNorm ----------------
__global__ __launch_bounds__(256) void wa_ln(
    const __bf16* __restrict__ Ag, const __bf16* __restrict__ WT,
    const float* __restrict__ bias, const float* __restrict__ xbase,
    const float* __restrict__ g, const float* __restrict__ bb,
    const float* __restrict__ skip, float* __restrict__ out, int M)
{
  int tid = threadIdx.x, l = tid & 63, wid = tid >> 6;
  int l15 = l & 15, l4 = l >> 4;
  int rowb = blockIdx.x * 64 + wid * 16;

  fvec4 z = {0.f, 0.f, 0.f, 0.f};
  fvec4 acc[8];
#pragma unroll
  for (int n = 0; n < 8; ++n) acc[n] = z;

#pragma unroll
  for (int ks = 0; ks < 4; ++ks) {
    int kb = ks * 32 + l4 * 8;
    int r = rowb + l15;
    r = r < M ? r : M - 1;
    bf16x8 af = *(const bf16x8*)(Ag + (size_t)r * 128 + kb);
#pragma unroll
    for (int n = 0; n < 8; ++n) {
      bf16x8 bfr = *(const bf16x8*)(WT + (size_t)(n * 16 + l15) * 128 + kb);
      acc[n] = __builtin_amdgcn_mfma_f32_16x16x32_bf16(af, bfr, acc[n], 0, 0, 0);
    }
  }

  float alpha = 1.f / (1.f + __expf(-skip[0]));
  float onema = 1.f - alpha;
  float o[8][4];
  float psum[4] = {0.f, 0.f, 0.f, 0.f};
  float psq[4] = {0.f, 0.f, 0.f, 0.f};
#pragma unroll
  for (int n = 0; n < 8; ++n) {
    int col = n * 16 + l15;
    float bcol = bias[col];
#pragma unroll
    for (int reg = 0; reg < 4; ++reg) {
      int r = rowb + l4 * 4 + reg;
      float xv = (r < M) ? xbase[(size_t)r * 128 + col] : 0.f;
      float val = (acc[n][reg] + bcol) * alpha + xv * onema;
      o[n][reg] = val;
      psum[reg] += val;
      psq[reg] = fmaf(val, val, psq[reg]);
    }
  }
#pragma unroll
  for (int reg = 0; reg < 4; ++reg) {
#pragma unroll
    for (int m = 1; m < 16; m <<= 1) {
      psum[reg] += __shfl_xor(psum[reg], m, 64);
      psq[reg] += __shfl_xor(psq[reg], m, 64);
    }
  }
  float mu[4], is[4];
#pragma unroll
  for (int reg = 0; reg < 4; ++reg) {
    mu[reg] = psum[reg] * (1.f / 128.f);
    float var = psq[reg] * (1.f / 128.f) - mu[reg] * mu[reg];
    is[reg] = 1.f / sqrtf(var + 1e-5f);
  }
#pragma unroll
  for (int n = 0; n < 8; ++n) {
    int col = n * 16 + l15;
    float gc = g[col], bc = bb[col];
#pragma unroll
    for (int reg = 0; reg < 4; ++reg) {
      int r = rowb + l4 * 4 + reg;
      if (r < M) out[(size_t)r * 128 + col] = (o[n][reg] - mu[reg]) * is[reg] * gc + bc;
    }
  }
}

// ---------------- launch ----------------
extern "C" void kernel_launch(void* const* d_in, const int* in_sizes, int n_in,
                              void* d_out, int out_size, void* d_ws, size_t ws_size,
                              hipStream_t stream)
{
  const float* x_a = (const float*)d_in[0];
  const float* x_b = (const float*)d_in[1];
  const float* ew0 = (const float*)d_in[2];
  const float* ew1 = (const float*)d_in[3];
  const int* src0 = (const int*)d_in[4];
  const int* dst0 = (const int*)d_in[5];
  const int* src1 = (const int*)d_in[6];
  const int* dst1 = (const int*)d_in[7];
  const float* Wk = (const float*)d_in[8];
  const float* bk = (const float*)d_in[9];
  const float* Wq = (const float*)d_in[10];
  const float* bq = (const float*)d_in[11];
  const float* Wv = (const float*)d_in[12];
  const float* bv = (const float*)d_in[13];
  const float* Wa = (const float*)d_in[14];
  const float* ba = (const float*)d_in[15];
  const float* ln_g = (const float*)d_in[16];
  const float* ln_b = (const float*)d_in[17];
  const float* rel_pri = (const float*)d_in[18];
  const float* rel_att = (const float*)d_in[19];
  const float* rel_msg = (const float*)d_in[20];
  const float* skip = (const float*)d_in[21];

  int NA = in_sizes[0] / 128, NB = in_sizes[1] / 128;
  int E0 = in_sizes[2], E1 = in_sizes[3];
  int NMAX = NA > NB ? NA : NB;
  int NM = (NMAX + 255) & ~255;
  int N2 = NA + NB;
  int N2M = (N2 + 255) & ~255;
  int E2 = E0 + E1;
  int E2M = (E2 + 255) & ~255;

  char* wsbase = (char*)d_ws;
  size_t off = 0;
  auto alloc = [&](size_t bytes) { char* p = wsbase + off; off += (bytes + 255) & ~(size_t)255; return p; };
  __bf16* kvb_a = (__bf16*)alloc((size_t)NM * 256 * 2);
  __bf16* kvb_b = (__bf16*)alloc((size_t)NM * 256 * 2);
  __bf16* qd_a  = (__bf16*)alloc((size_t)NM * 128 * 2);
  __bf16* qd_b  = (__bf16*)alloc((size_t)NM * 128 * 2);
  __bf16* agg_a = (__bf16*)alloc((size_t)NM * 128 * 2);
  __bf16* agg_b = (__bf16*)alloc((size_t)NM * 128 * 2);
  __bf16* WkvqT = (__bf16*)alloc(2 * 384 * 128 * 2);
  __bf16* WaT   = (__bf16*)alloc(2 * 128 * 128 * 2);
  float* bkvq   = (float*)alloc(2 * 384 * 4);
  int* deg      = (int*)alloc((size_t)N2M * 4);
  int* row_st   = (int*)alloc((size_t)N2M * 4);
  int* cur      = (int*)alloc((size_t)N2M * 4);
  int* partial  = (int*)alloc(1024 * 4);
  int* pscan    = (int*)alloc(1024 * 4);
  int* sidx     = (int*)alloc((size_t)E2M * 4);
  float* ewc    = (float*)alloc((size_t)E2M * 4);

  float* outf = (float*)d_out;
  dim3 b256(256);
  auto cdiv = [](int a, int b) { return (unsigned)((a + b - 1) / b); };

  // weights prep
  fuse_w<<<dim3(129, 2), b256, 0, stream>>>(Wk, bk, Wv, bv, rel_att, rel_msg, WkvqT, bkvq);
  cvt_wT<<<dim3(128, 2, 2), 128, 0, stream>>>(Wq, bq, Wa, WkvqT, WaT, bkvq);

  // CSR for both relations, concatenated [NB | NA]
  int NP = (N2 + 1023) / 1024;
  fzero<<<64, b256, 0, stream>>>((float*)deg, N2);
  csr_count2<<<cdiv(E2, 256), b256, 0, stream>>>(dst0, E0, dst1, E1, deg, NB);
  csr_partial<<<NP, b256, 0, stream>>>(deg, N2, partial);
  csr_scan_partials<<<1, 64, 0, stream>>>(partial, pscan, NP);
  csr_scan_chunk<<<NP, b256, 0, stream>>>(deg, pscan, row_st, cur, N2);
  csr_scatter2<<<cdiv(E2, 256), b256, 0, stream>>>(dst0, src0, ew0, E0,
                                                   dst1, src1, ew1, E1,
                                                   cur, sidx, ewc, NB);

  // ---- fused projections: one GEMM per node type (x read once) ----
  gemm_kvq<<<cdiv(NA, 64), b256, 0, stream>>>(x_a, NA, WkvqT, bkvq, kvb_a, qd_a);
  gemm_kvq<<<cdiv(NB, 64), b256, 0, stream>>>(x_b, NB, WkvqT + 49152, bkvq + 384, kvb_b, qd_b);

  // ---- attention ----
  hgt_dst<<<cdiv(NB, 4), b256, 0, stream>>>(kvb_a, qd_b, row_st, deg, sidx, ewc,
                                            rel_pri, agg_b, NB);
  hgt_dst<<<cdiv(NA, 4), b256, 0, stream>>>(kvb_b, qd_a, row_st + NB, deg + NB, sidx, ewc,
                                            rel_pri + 8, agg_a, NA);

  // ---- fused Wa projection + skip + LayerNorm ----
  wa_ln<<<cdiv(NA, 64), b256, 0, stream>>>(agg_a, WaT, ba, x_a, ln_g, ln_b, skip, outf, NA);
  wa_ln<<<cdiv(NB, 64), b256, 0, stream>>>(agg_b, WaT + 16384, ba + 128, x_b,
                                           ln_g + 128, ln_b + 128, skip + 1,
                                           outf + (size_t)NA * 128, NB);
}

// Round 9
// 582.799 us; speedup vs baseline: 11.6170x; 1.0764x over previous
//
#include <hip/hip_runtime.h>
#include <cstdint>
#include <cstddef>

#define EPSF 1e-9f

typedef __bf16 bf16x8 __attribute__((ext_vector_type(8)));
typedef float fvec4 __attribute__((ext_vector_type(4)));

__device__ __forceinline__ float blo(unsigned int u) { return __uint_as_float(u << 16); }
__device__ __forceinline__ float bhi(unsigned int u) { return __uint_as_float(u & 0xffff0000u); }
__device__ __forceinline__ unsigned short f2bf(float f) {
  unsigned int u = __float_as_uint(f);
  u += 0x7fffu + ((u >> 16) & 1u);
  return (unsigned short)(u >> 16);
}
__device__ __forceinline__ unsigned int pack2bf(float a, float b) {
  return (unsigned int)f2bf(a) | ((unsigned int)f2bf(b) << 16);
}

// ---------------- zero ----------------
__global__ __launch_bounds__(256) void fzero(float* __restrict__ p, long n) {
  long i = (long)blockIdx.x * blockDim.x + threadIdx.x;
  long stride = (long)gridDim.x * blockDim.x;
  long n4 = n >> 2;
  float4* p4 = (float4*)p;
  for (long j = i; j < n4; j += stride) p4[j] = make_float4(0.f, 0.f, 0.f, 0.f);
  for (long j = (n4 << 2) + i; j < n; j += stride) p[j] = 0.f;
}

// ---- fold rel_att/rel_msg into Wk/Wv -> rows 0..255 of WkvqT[t] ([384 cols][128 k], bf16) ----
__global__ __launch_bounds__(256) void fuse_w(
    const float* __restrict__ Wk, const float* __restrict__ bk,
    const float* __restrict__ Wv, const float* __restrict__ bv,
    const float* __restrict__ rel_att, const float* __restrict__ rel_msg,
    __bf16* __restrict__ WkvqT, float* __restrict__ bkvq)
{
  int i = blockIdx.x;   // 0..128 (128 == bias row)
  int t = blockIdx.y;
  int c = threadIdx.x;  // 0..255: [0,128)=k cols, [128,256)=v cols
  int m = c >> 7, cc = c & 127;
  int h = cc >> 4, e = cc & 15;
  const float* R = (m ? rel_msg : rel_att) + t * 2048 + h * 256;
  const float* srcW = (m ? Wv : Wk) + t * 16384;
  const float* srcB = (m ? bv : bk) + t * 128;
  const float* row = (i < 128) ? (srcW + i * 128) : srcB;
  float acc = 0.f;
#pragma unroll
  for (int d = 0; d < 16; ++d) acc = fmaf(row[h * 16 + d], R[d * 16 + e], acc);
  if (i < 128) WkvqT[(size_t)t * 49152 + (size_t)c * 128 + i] = (__bf16)acc;
  else         bkvq[t * 384 + c] = acc;
}

// ---- Wq -> rows 256..383 of WkvqT[t] (+q bias); Wa -> WaT [t][col][k] ----
__global__ __launch_bounds__(128) void cvt_wT(
    const float* __restrict__ Wq, const float* __restrict__ bq,
    const float* __restrict__ Wa,
    __bf16* __restrict__ WkvqT, __bf16* __restrict__ WaT,
    float* __restrict__ bkvq)
{
  int k = blockIdx.x, t = blockIdx.y, c = threadIdx.x;
  if (blockIdx.z == 0) {
    WkvqT[(size_t)t * 49152 + (size_t)(256 + c) * 128 + k] = (__bf16)Wq[t * 16384 + k * 128 + c];
    if (k == 0) bkvq[t * 384 + 256 + c] = bq[t * 128 + c];
  } else {
    WaT[(size_t)t * 16384 + (size_t)c * 128 + k] = (__bf16)Wa[t * 16384 + k * 128 + c];
  }
}

// ---------------- fused KVQ MFMA GEMM, both node types in one dispatch ----------------
// [KV(256) | Q(128)] = A[Mx128 f32] @ WT[384x128]. Block 64 rows, 4 waves (2m x 2n).
// A staged to LDS as bf16 (XOR-swizzled). MFMA operands SWAPPED (mfma(W,X) -> C^T
// fragment): lane holds 4 consecutive output cols of one row -> uint2 (8B) stores.
__global__ __launch_bounds__(256) void gemm_kvq(
    const float* __restrict__ Aa, int Ma, const float* __restrict__ Ab, int Mb, int nblk_a,
    const __bf16* __restrict__ WTall, const float* __restrict__ ball,
    __bf16* __restrict__ KVa, __bf16* __restrict__ Qa,
    __bf16* __restrict__ KVb, __bf16* __restrict__ Qb)
{
  __shared__ __bf16 As[64 * 128];  // 16 KB, byte ^= (row&7)<<4
  const int tid = threadIdx.x;
  const bool isA = blockIdx.x < (unsigned)nblk_a;
  const int blk = isA ? blockIdx.x : blockIdx.x - nblk_a;
  const float* A = isA ? Aa : Ab;
  const int M = isA ? Ma : Mb;
  const __bf16* WT = WTall + (isA ? 0 : 49152);
  const float* bs = ball + (isA ? 0 : 384);
  __bf16* KV = isA ? KVa : KVb;
  __bf16* Q  = isA ? Qa : Qb;
  const int rowb = blk * 64;

#pragma unroll
  for (int i = 0; i < 4; ++i) {     // stage+convert, conversion off the MFMA path
    int f = tid + i * 256;
    int r = f >> 4, ch = f & 15;
    int gr = rowb + r; gr = gr < M ? gr : M - 1;
    const float4* ap = (const float4*)(A + (size_t)gr * 128 + ch * 8);
    float4 a0 = ap[0], a1 = ap[1];
    bf16x8 v;
    v[0] = (__bf16)a0.x; v[1] = (__bf16)a0.y; v[2] = (__bf16)a0.z; v[3] = (__bf16)a0.w;
    v[4] = (__bf16)a1.x; v[5] = (__bf16)a1.y; v[6] = (__bf16)a1.z; v[7] = (__bf16)a1.w;
    int sw = (ch * 16) ^ ((r & 7) << 4);
    *(bf16x8*)((char*)As + r * 256 + sw) = v;
  }
  __syncthreads();

  const int l = tid & 63, wid = tid >> 6;
  const int l15 = l & 15, l4 = l >> 4;
  const int wm = wid & 1, wn = wid >> 1;

  bf16x8 af[2][4];                  // X-frags, reused across the 3 col tiles
#pragma unroll
  for (int m = 0; m < 2; ++m)
#pragma unroll
    for (int ks = 0; ks < 4; ++ks) {
      int r = wm * 32 + m * 16 + l15;
      int off = (ks * 64 + l4 * 16) ^ ((r & 7) << 4);
      af[m][ks] = *(const bf16x8*)((const char*)As + r * 256 + off);
    }

#pragma unroll
  for (int t = 0; t < 3; ++t) {     // tiles 0,1 -> KV; 2 -> Q
    const int colb = t * 128 + wn * 64;
    fvec4 z = {0.f, 0.f, 0.f, 0.f};
    fvec4 acc[2][4];
#pragma unroll
    for (int m = 0; m < 2; ++m)
#pragma unroll
      for (int n = 0; n < 4; ++n) acc[m][n] = z;

    bf16x8 bfr[4][4];
#pragma unroll
    for (int n = 0; n < 4; ++n)
#pragma unroll
      for (int ks = 0; ks < 4; ++ks)
        bfr[n][ks] = *(const bf16x8*)(WT + (size_t)(colb + n * 16 + l15) * 128 + ks * 32 + l4 * 8);

#pragma unroll
    for (int ks = 0; ks < 4; ++ks)
#pragma unroll
      for (int m = 0; m < 2; ++m)
#pragma unroll
        for (int n = 0; n < 4; ++n)   // swapped operands -> transposed fragment
          acc[m][n] = __builtin_amdgcn_mfma_f32_16x16x32_bf16(bfr[n][ks], af[m][ks], acc[m][n], 0, 0, 0);

#pragma unroll
    for (int m = 0; m < 2; ++m) {
      int r = rowb + wm * 32 + m * 16 + l15;
      if (r >= M) continue;
#pragma unroll
      for (int n = 0; n < 4; ++n) {
        int cb = colb + n * 16 + l4 * 4;    // 4 consecutive cols
        fvec4 b4 = *(const fvec4*)(bs + cb);
        uint2 w;
        w.x = pack2bf(acc[m][n][0] + b4[0], acc[m][n][1] + b4[1]);
        w.y = pack2bf(acc[m][n][2] + b4[2], acc[m][n][3] + b4[3]);
        if (t < 2) *(uint2*)(KV + (size_t)r * 256 + cb) = w;
        else       *(uint2*)(Q + (size_t)r * 128 + (cb - 256)) = w;
      }
    }
  }
}

// ---------------- CSR build (both relations concatenated: [NB dsts | NA dsts]) ----------------
__global__ __launch_bounds__(256) void csr_count2(
    const int* __restrict__ dst0, int E0, const int* __restrict__ dst1, int E1,
    int* __restrict__ deg, int NB)
{
  int e = blockIdx.x * 256 + threadIdx.x;
  if (e < E0) atomicAdd(&deg[dst0[e]], 1);
  else if (e < E0 + E1) atomicAdd(&deg[NB + dst1[e - E0]], 1);
}

__global__ __launch_bounds__(256) void csr_partial(
    const int* __restrict__ deg, int N, int* __restrict__ partial)
{
  int base = blockIdx.x * 1024 + threadIdx.x * 4;
  int s = 0;
#pragma unroll
  for (int i = 0; i < 4; ++i) if (base + i < N) s += deg[base + i];
#pragma unroll
  for (int m = 1; m < 64; m <<= 1) s += __shfl_xor(s, m, 64);
  __shared__ int wsum[4];
  if ((threadIdx.x & 63) == 0) wsum[threadIdx.x >> 6] = s;
  __syncthreads();
  if (threadIdx.x == 0) partial[blockIdx.x] = wsum[0] + wsum[1] + wsum[2] + wsum[3];
}

__global__ void csr_scan_partials(const int* __restrict__ partial,
                                  int* __restrict__ pscan, int NP)
{
  if (blockIdx.x == 0 && threadIdx.x == 0) {
    int s = 0;
    for (int i = 0; i < NP; ++i) { pscan[i] = s; s += partial[i]; }
  }
}

__global__ __launch_bounds__(256) void csr_scan_chunk(
    const int* __restrict__ deg, const int* __restrict__ pscan,
    int* __restrict__ row_start, int* __restrict__ cursor, int N)
{
  __shared__ int ls[256];
  int base = blockIdx.x * 1024 + threadIdx.x * 4;
  int v0 = 0, v1 = 0, v2 = 0, v3 = 0;
  if (base + 0 < N) v0 = deg[base + 0];
  if (base + 1 < N) v1 = deg[base + 1];
  if (base + 2 < N) v2 = deg[base + 2];
  if (base + 3 < N) v3 = deg[base + 3];
  int s = v0 + v1 + v2 + v3;
  ls[threadIdx.x] = s;
  __syncthreads();
  for (int off = 1; off < 256; off <<= 1) {
    int t = (threadIdx.x >= off) ? ls[threadIdx.x - off] : 0;
    __syncthreads();
    ls[threadIdx.x] += t;
    __syncthreads();
  }
  int excl = pscan[blockIdx.x] + ls[threadIdx.x] - s;
  int p0 = excl, p1 = excl + v0, p2 = excl + v0 + v1, p3 = excl + v0 + v1 + v2;
  if (base + 0 < N) { row_start[base + 0] = p0; cursor[base + 0] = p0; }
  if (base + 1 < N) { row_start[base + 1] = p1; cursor[base + 1] = p1; }
  if (base + 2 < N) { row_start[base + 2] = p2; cursor[base + 2] = p2; }
  if (base + 3 < N) { row_start[base + 3] = p3; cursor[base + 3] = p3; }
}

__global__ __launch_bounds__(256) void csr_scatter2(
    const int* __restrict__ dst0, const int* __restrict__ src0, const float* __restrict__ ew0, int E0,
    const int* __restrict__ dst1, const int* __restrict__ src1, const float* __restrict__ ew1, int E1,
    int* __restrict__ cursor, int* __restrict__ sidx, float* __restrict__ ewc, int NB)
{
  int e = blockIdx.x * 256 + threadIdx.x;
  if (e < E0) {
    int p = atomicAdd(&cursor[dst0[e]], 1);
    sidx[p] = src0[e];
    ewc[p] = fmaxf(ew0[e], 0.f);
  } else if (e < E0 + E1) {
    int e1 = e - E0;
    int p = atomicAdd(&cursor[NB + dst1[e1]], 1);
    sidx[p] = src1[e1];
    ewc[p] = fmaxf(ew1[e1], 0.f);
  }
}

// ---------------- fused per-dst attention, both relations in one dispatch ----------------
__device__ __forceinline__ void proc_edge(
    float qlo, float qhi, unsigned int ku, unsigned int vu, float w,
    float inv_den, float pr, float& s, float2& acc)
{
  float t = qlo * blo(ku) + qhi * bhi(ku);
  t += __shfl_xor(t, 1, 64);
  t += __shfl_xor(t, 2, 64);
  t += __shfl_xor(t, 4, 64);             // 16-dim head dot broadcast in 8-lane group
  float x = __expf((t + __logf(w * inv_den + EPSF)) * pr);
  s += x;
  acc.x = fmaf(x, blo(vu), acc.x);
  acc.y = fmaf(x, bhi(vu), acc.y);
}

// one 64-lane wave per dst node (global id over [NB|NA]); lane owns 2 dims
__global__ __launch_bounds__(256) void hgt_dst(
    const __bf16* __restrict__ kv0, const __bf16* __restrict__ q0,
    const __bf16* __restrict__ kv1, const __bf16* __restrict__ q1,
    const int* __restrict__ row_start, const int* __restrict__ deg,
    const int* __restrict__ sidx, const float* __restrict__ ewc,
    const float* __restrict__ pri16,
    __bf16* __restrict__ agg0, __bf16* __restrict__ agg1, int NB, int N2)
{
  int n = (blockIdx.x * 256 + threadIdx.x) >> 6;
  int lane = threadIdx.x & 63;
  if (n >= N2) return;
  bool g0 = n < NB;
  int nl = g0 ? n : n - NB;
  const unsigned short* kvs = (const unsigned short*)(g0 ? kv0 : kv1);
  const unsigned short* qrow = (const unsigned short*)(g0 ? q0 : q1) + (size_t)nl * 128;
  const float* pri8 = pri16 + (g0 ? 0 : 8);
  int c0 = lane * 2;
  unsigned int* out = (unsigned int*)((g0 ? agg0 : agg1) + (size_t)nl * 128 + c0);
  int d = deg[n];
  if (d == 0) { out[0] = 0u; return; }
  int base = row_start[n];

  float ds = 0.f;
  for (int j = lane; j < d; j += 64) ds += ewc[base + j];
#pragma unroll
  for (int m = 1; m < 64; m <<= 1) ds += __shfl_xor(ds, m, 64);
  float inv_den = 1.f / fmaxf(ds, EPSF);

  int h = lane >> 3;
  float pr = pri8[h] * 0.25f;            // pri / sqrt(DK)
  unsigned int qu = *(const unsigned int*)(qrow + c0);
  float qlo = blo(qu), qhi = bhi(qu);

  float s = 0.f;
  float2 acc = make_float2(0.f, 0.f);
  int j = 0;
  for (; j + 4 <= d; j += 4) {           // batch 4 edges: 8 gathers in flight
    int b = base + j;
    int si0 = sidx[b], si1 = sidx[b + 1], si2 = sidx[b + 2], si3 = sidx[b + 3];
    float w0 = ewc[b], w1 = ewc[b + 1], w2 = ewc[b + 2], w3 = ewc[b + 3];
    const unsigned short* p0 = kvs + (size_t)si0 * 256 + c0;
    const unsigned short* p1 = kvs + (size_t)si1 * 256 + c0;
    const unsigned short* p2 = kvs + (size_t)si2 * 256 + c0;
    const unsigned short* p3 = kvs + (size_t)si3 * 256 + c0;
    unsigned int k0 = *(const unsigned int*)p0, v0 = *(const unsigned int*)(p0 + 128);
    unsigned int k1 = *(const unsigned int*)p1, v1 = *(const unsigned int*)(p1 + 128);
    unsigned int k2 = *(const unsigned int*)p2, v2 = *(const unsigned int*)(p2 + 128);
    unsigned int k3 = *(const unsigned int*)p3, v3 = *(const unsigned int*)(p3 + 128);
    proc_edge(qlo, qhi, k0, v0, w0, inv_den, pr, s, acc);
    proc_edge(qlo, qhi, k1, v1, w1, inv_den, pr, s, acc);
    proc_edge(qlo, qhi, k2, v2, w2, inv_den, pr, s, acc);
    proc_edge(qlo, qhi, k3, v3, w3, inv_den, pr, s, acc);
  }
  for (; j < d; ++j) {
    int b = base + j;
    const unsigned short* p = kvs + (size_t)sidx[b] * 256 + c0;
    proc_edge(qlo, qhi, *(const unsigned int*)p, *(const unsigned int*)(p + 128),
              ewc[b], inv_den, pr, s, acc);
  }
  float is = 1.f / s;
  out[0] = pack2bf(acc.x * is, acc.y * is);
}

// ---------------- fused Wa-projection + skip-mix + LayerNorm (both types) ----------------
// wave owns 16 rows; SWAPPED mfma -> lane holds 4 consecutive cols of row (l15):
// float4 xbase reads, float4 out stores, LN reduce = 2 shuffles (across l4 lanes).
__global__ __launch_bounds__(256) void wa_ln(
    const __bf16* __restrict__ Ag_a, const __bf16* __restrict__ Ag_b,
    const __bf16* __restrict__ WaT, const float* __restrict__ ba,
    const float* __restrict__ x_a, const float* __restrict__ x_b,
    const float* __restrict__ lng, const float* __restrict__ lnb,
    const float* __restrict__ skip, float* __restrict__ out,
    int NA, int NB, int nblk_a)
{
  const int tid = threadIdx.x, l = tid & 63, wid = tid >> 6;
  const int l15 = l & 15, l4 = l >> 4;
  const bool isA = blockIdx.x < (unsigned)nblk_a;
  const int blk = isA ? blockIdx.x : blockIdx.x - nblk_a;
  const int M = isA ? NA : NB;
  const __bf16* Ag = isA ? Ag_a : Ag_b;
  const __bf16* WT = WaT + (isA ? 0 : 16384);
  const float* bias = ba + (isA ? 0 : 128);
  const float* xb = isA ? x_a : x_b;
  const float* g = lng + (isA ? 0 : 128);
  const float* bb = lnb + (isA ? 0 : 128);
  float* o = out + (isA ? (size_t)0 : (size_t)NA * 128);
  const int rowb = blk * 64 + wid * 16;
  const int r = rowb + l15;
  const int rc = r < M ? r : M - 1;

  bf16x8 af[4];
#pragma unroll
  for (int ks = 0; ks < 4; ++ks)
    af[ks] = *(const bf16x8*)(Ag + (size_t)rc * 128 + ks * 32 + l4 * 8);

  fvec4 z = {0.f, 0.f, 0.f, 0.f};
  fvec4 acc[8];
#pragma unroll
  for (int n = 0; n < 8; ++n) acc[n] = z;
#pragma unroll
  for (int ks = 0; ks < 4; ++ks)
#pragma unroll
    for (int n = 0; n < 8; ++n) {
      bf16x8 wf = *(const bf16x8*)(WT + (size_t)(n * 16 + l15) * 128 + ks * 32 + l4 * 8);
      acc[n] = __builtin_amdgcn_mfma_f32_16x16x32_bf16(wf, af[ks], acc[n], 0, 0, 0);
    }

  float alpha = 1.f / (1.f + __expf(-skip[isA ? 0 : 1]));
  float onema = 1.f - alpha;
  float vals[8][4];
  float psum = 0.f, psq = 0.f;
#pragma unroll
  for (int n = 0; n < 8; ++n) {
    int cb = n * 16 + l4 * 4;
    fvec4 b4 = *(const fvec4*)(bias + cb);
    fvec4 xv = *(const fvec4*)(xb + (size_t)rc * 128 + cb);
#pragma unroll
    for (int reg = 0; reg < 4; ++reg) {
      float v = (acc[n][reg] + b4[reg]) * alpha + xv[reg] * onema;
      vals[n][reg] = v;
      psum += v;
      psq = fmaf(v, v, psq);
    }
  }
  psum += __shfl_xor(psum, 16, 64); psq += __shfl_xor(psq, 16, 64);
  psum += __shfl_xor(psum, 32, 64); psq += __shfl_xor(psq, 32, 64);
  float mu = psum * (1.f / 128.f);
  float var = psq * (1.f / 128.f) - mu * mu;
  float is = 1.f / sqrtf(var + 1e-5f);

  if (r < M) {
#pragma unroll
    for (int n = 0; n < 8; ++n) {
      int cb = n * 16 + l4 * 4;
      fvec4 g4 = *(const fvec4*)(g + cb);
      fvec4 bb4 = *(const fvec4*)(bb + cb);
      fvec4 ov;
#pragma unroll
      for (int reg = 0; reg < 4; ++reg)
        ov[reg] = (vals[n][reg] - mu) * is * g4[reg] + bb4[reg];
      *(fvec4*)(o + (size_t)r * 128 + cb) = ov;
    }
  }
}

// ---------------- launch ----------------
extern "C" void kernel_launch(void* const* d_in, const int* in_sizes, int n_in,
                              void* d_out, int out_size, void* d_ws, size_t ws_size,
                              hipStream_t stream)
{
  const float* x_a = (const float*)d_in[0];
  const float* x_b = (const float*)d_in[1];
  const float* ew0 = (const float*)d_in[2];
  const float* ew1 = (const float*)d_in[3];
  const int* src0 = (const int*)d_in[4];
  const int* dst0 = (const int*)d_in[5];
  const int* src1 = (const int*)d_in[6];
  const int* dst1 = (const int*)d_in[7];
  const float* Wk = (const float*)d_in[8];
  const float* bk = (const float*)d_in[9];
  const float* Wq = (const float*)d_in[10];
  const float* bq = (const float*)d_in[11];
  const float* Wv = (const float*)d_in[12];
  const float* bv = (const float*)d_in[13];
  const float* Wa = (const float*)d_in[14];
  const float* ba = (const float*)d_in[15];
  const float* ln_g = (const float*)d_in[16];
  const float* ln_b = (const float*)d_in[17];
  const float* rel_pri = (const float*)d_in[18];
  const float* rel_att = (const float*)d_in[19];
  const float* rel_msg = (const float*)d_in[20];
  const float* skip = (const float*)d_in[21];

  int NA = in_sizes[0] / 128, NB = in_sizes[1] / 128;
  int E0 = in_sizes[2], E1 = in_sizes[3];
  int NMAX = NA > NB ? NA : NB;
  int NM = (NMAX + 255) & ~255;
  int N2 = NA + NB;
  int N2M = (N2 + 255) & ~255;
  int E2 = E0 + E1;
  int E2M = (E2 + 255) & ~255;

  char* wsbase = (char*)d_ws;
  size_t off = 0;
  auto alloc = [&](size_t bytes) { char* p = wsbase + off; off += (bytes + 255) & ~(size_t)255; return p; };
  __bf16* kvb_a = (__bf16*)alloc((size_t)NM * 256 * 2);
  __bf16* kvb_b = (__bf16*)alloc((size_t)NM * 256 * 2);
  __bf16* qd_a  = (__bf16*)alloc((size_t)NM * 128 * 2);
  __bf16* qd_b  = (__bf16*)alloc((size_t)NM * 128 * 2);
  __bf16* agg_a = (__bf16*)alloc((size_t)NM * 128 * 2);
  __bf16* agg_b = (__bf16*)alloc((size_t)NM * 128 * 2);
  __bf16* WkvqT = (__bf16*)alloc(2 * 384 * 128 * 2);
  __bf16* WaT   = (__bf16*)alloc(2 * 128 * 128 * 2);
  float* bkvq   = (float*)alloc(2 * 384 * 4);
  int* deg      = (int*)alloc((size_t)N2M * 4);
  int* row_st   = (int*)alloc((size_t)N2M * 4);
  int* cur      = (int*)alloc((size_t)N2M * 4);
  int* partial  = (int*)alloc(1024 * 4);
  int* pscan    = (int*)alloc(1024 * 4);
  int* sidx     = (int*)alloc((size_t)E2M * 4);
  float* ewc    = (float*)alloc((size_t)E2M * 4);

  float* outf = (float*)d_out;
  dim3 b256(256);
  auto cdiv = [](int a, int b) { return (unsigned)((a + b - 1) / b); };

  // weights prep
  fuse_w<<<dim3(129, 2), b256, 0, stream>>>(Wk, bk, Wv, bv, rel_att, rel_msg, WkvqT, bkvq);
  cvt_wT<<<dim3(128, 2, 2), 128, 0, stream>>>(Wq, bq, Wa, WkvqT, WaT, bkvq);

  // CSR for both relations, concatenated [NB | NA]
  int NP = (N2 + 1023) / 1024;
  fzero<<<64, b256, 0, stream>>>((float*)deg, N2);
  csr_count2<<<cdiv(E2, 256), b256, 0, stream>>>(dst0, E0, dst1, E1, deg, NB);
  csr_partial<<<NP, b256, 0, stream>>>(deg, N2, partial);
  csr_scan_partials<<<1, 64, 0, stream>>>(partial, pscan, NP);
  csr_scan_chunk<<<NP, b256, 0, stream>>>(deg, pscan, row_st, cur, N2);
  csr_scatter2<<<cdiv(E2, 256), b256, 0, stream>>>(dst0, src0, ew0, E0,
                                                   dst1, src1, ew1, E1,
                                                   cur, sidx, ewc, NB);

  // ---- fused projections: both node types, one dispatch ----
  int nba = cdiv(NA, 64), nbb = cdiv(NB, 64);
  gemm_kvq<<<nba + nbb, b256, 0, stream>>>(x_a, NA, x_b, NB, nba, WkvqT, bkvq,
                                           kvb_a, qd_a, kvb_b, qd_b);

  // ---- attention: both relations, one dispatch ----
  hgt_dst<<<cdiv(N2, 4), b256, 0, stream>>>(kvb_a, qd_b, kvb_b, qd_a,
                                            row_st, deg, sidx, ewc, rel_pri,
                                            agg_b, agg_a, NB, N2);

  // ---- fused Wa projection + skip + LayerNorm: both types, one dispatch ----
  wa_ln<<<nba + nbb, b256, 0, stream>>>(agg_a, agg_b, WaT, ba, x_a, x_b,
                                        ln_g, ln_b, skip, outf, NA, NB, nba);
}